// Round 2
// baseline (973.941 us; speedup 1.0000x reference)
//
#include <hip/hip_runtime.h>
#include <cstdint>
#include <cstddef>

#define B_ 4
#define C_ 64
#define C4_ 16
#define D_ 128
#define H_ 64
#define W_ 64
#define L_ 4096
#define K_ 4
#define N_ 16
#define R_ 4
#define NC_ 64
#define CL_ 64
#define EPS_ 1e-6f

#define DEV __device__ __forceinline__

DEV float sigmoidf_(float x){ return 1.f/(1.f+__expf(-x)); }
DEV float siluf_(float x){ return x*sigmoidf_(x); }
// fast softplus: max(x,0) + log(1+exp(-|x|)); arg of log in [1,2] -> __logf fine
DEV float softplusf_(float x){ return fmaxf(x,0.f) + __logf(1.f+__expf(-fabsf(x))); }

// ---------------------------------------------------------------------------
// K1: q1 = LN16( conv1x1(x, wt_dw) + wt_db )   -> (B,16,H,W)
// 256 blocks x 64 threads: one wave per CU, weights wave-uniform
__global__ __launch_bounds__(64) void k1_inln(
    const float* __restrict__ x, const float* __restrict__ w,
    const float* __restrict__ bias, const float* __restrict__ g,
    const float* __restrict__ bb, float* __restrict__ q1)
{
  int t = blockIdx.x*64 + threadIdx.x;
  int b = t >> 12; int pix = t & (L_-1);
  const float* xb = x + (size_t)b*C_*L_ + pix;
  float acc[C4_];
  #pragma unroll
  for(int o=0;o<C4_;o++) acc[o] = bias[o];
  for(int c=0;c<C_;c++){
    float xv = xb[(size_t)c*L_];
    #pragma unroll
    for(int o=0;o<C4_;o++) acc[o] = fmaf(w[o*C_+c], xv, acc[o]);
  }
  float m=0.f;
  #pragma unroll
  for(int o=0;o<C4_;o++) m += acc[o];
  m *= (1.f/C4_);
  float var=0.f;
  #pragma unroll
  for(int o=0;o<C4_;o++){ float d=acc[o]-m; var += d*d; }
  var *= (1.f/C4_);
  float rs = rsqrtf(var+EPS_);
  float* qb = q1 + (size_t)b*C4_*L_ + pix;
  #pragma unroll
  for(int o=0;o<C4_;o++) qb[(size_t)o*L_] = (acc[o]-m)*rs*g[o] + bb[o];
}

// ---------------------------------------------------------------------------
// K2a: q2 = transposed-conv2x2( DWT_haar(q1) ) + ctb   -> (B,64,H,W)
__global__ __launch_bounds__(256) void k2a_dwtct(
    const float* __restrict__ q1, const float* __restrict__ ctw,
    const float* __restrict__ ctb, float* __restrict__ q2)
{
  int t = blockIdx.x*256 + threadIdx.x;      // ((b*4+quarter)*L + pix)
  int pix = t & (L_-1);
  int bq = t >> 12; int b = bq >> 2; int quarter = bq & 3;
  int y = pix >> 6, xw = pix & 63;
  int i = y >> 1, p = y & 1, j = xw >> 1, q = xw & 1;
  const float* qb = q1 + (size_t)b*C4_*L_;
  int p00 = (2*i)*W_ + 2*j;
  float ll[16], hl[16], lh[16], hh[16];
  #pragma unroll
  for(int c=0;c<16;c++){
    const float* pc = qb + (size_t)c*L_ + p00;
    float a = pc[0], bb2 = pc[1], cc = pc[W_], dd = pc[W_+1];
    ll[c] = (a+bb2+cc+dd)*0.5f;
    hl[c] = (bb2-a+dd-cc)*0.5f;
    lh[c] = (cc-a+dd-bb2)*0.5f;
    hh[c] = (a-bb2-cc+dd)*0.5f;
  }
  int pq = p*2+q;
  int obase = quarter*16;
  float* q2b = q2 + (size_t)b*C_*L_ + pix;
  #pragma unroll
  for(int oo=0;oo<16;oo++){
    int o = obase+oo;
    float acc = ctb[o];
    const float* wb = ctw + o*4 + pq;        // ctw[c][o][p][q], c-stride 256
    #pragma unroll
    for(int c=0;c<16;c++){
      acc = fmaf(ll[c], wb[c*256],       acc);
      acc = fmaf(hl[c], wb[(16+c)*256],  acc);
      acc = fmaf(lh[c], wb[(32+c)*256],  acc);
      acc = fmaf(hh[c], wb[(48+c)*256],  acc);
    }
    q2b[(size_t)o*L_] = acc;
  }
}

// ---------------------------------------------------------------------------
// K2b: skip = LN64( conv1x1(q2, cv_inw) )   -> (B,64,H,W)
__global__ __launch_bounds__(64) void k2b_inconv_ln(
    const float* __restrict__ q2, const float* __restrict__ w,
    const float* __restrict__ g, const float* __restrict__ bb,
    float* __restrict__ skip)
{
  int t = blockIdx.x*64 + threadIdx.x;
  int b = t >> 12; int pix = t & (L_-1);
  const float* qb = q2 + (size_t)b*C_*L_ + pix;
  float acc[C_];
  #pragma unroll
  for(int o=0;o<C_;o++) acc[o]=0.f;
  for(int c=0;c<C_;c++){
    float xv = qb[(size_t)c*L_];
    #pragma unroll
    for(int o=0;o<C_;o++) acc[o] = fmaf(w[o*C_+c], xv, acc[o]);
  }
  float m=0.f;
  #pragma unroll
  for(int o=0;o<C_;o++) m += acc[o];
  m *= (1.f/C_);
  float var=0.f;
  #pragma unroll
  for(int o=0;o<C_;o++){ float d=acc[o]-m; var += d*d; }
  var *= (1.f/C_);
  float rs = rsqrtf(var+EPS_);
  float* sb = skip + (size_t)b*C_*L_ + pix;
  #pragma unroll
  for(int o=0;o<C_;o++) sb[(size_t)o*L_] = (acc[o]-m)*rs*g[o] + bb[o];
}

// ---------------------------------------------------------------------------
// K3: hp = conv1x1(skip, cv_pw)   (64 -> 128)
__global__ __launch_bounds__(256) void k3_pw(
    const float* __restrict__ skip, const float* __restrict__ w,
    float* __restrict__ hp)
{
  int t = blockIdx.x*256 + threadIdx.x;      // ((b*8+grp)*L + pix)
  int pix = t & (L_-1);
  int bg = t >> 12; int b = bg >> 3; int grp = bg & 7;
  const float* sb = skip + (size_t)b*C_*L_ + pix;
  float acc[16];
  #pragma unroll
  for(int o=0;o<16;o++) acc[o]=0.f;
  for(int c=0;c<C_;c++){
    float xv = sb[(size_t)c*L_];
    #pragma unroll
    for(int oo=0;oo<16;oo++) acc[oo]=fmaf(w[(grp*16+oo)*C_+c], xv, acc[oo]);
  }
  float* hb = hp + (size_t)b*D_*L_ + (size_t)(grp*16)*L_ + pix;
  #pragma unroll
  for(int oo=0;oo<16;oo++) hb[(size_t)oo*L_] = acc[oo];
}

// ---------------------------------------------------------------------------
// K4: hd = silu(dw3x3(hp)+cv_dwb); hdt = spatial transpose of hd.
__global__ __launch_bounds__(256) void k4_dwsilu(
    const float* __restrict__ hp, const float* __restrict__ wdw,
    const float* __restrict__ bdw, float* __restrict__ hd,
    float* __restrict__ hdt)
{
  __shared__ float tin[64][65];
  __shared__ float tout[64][65];
  int bc = blockIdx.x;                       // b*D_ + ch
  int ch = bc & (D_-1);
  const float* plane = hp + (size_t)bc*L_;
  int tid = threadIdx.x;
  #pragma unroll
  for(int qq=0;qq<16;qq++){ int lin = tid + qq*256; tin[lin>>6][lin&63] = plane[lin]; }
  __syncthreads();
  float wv[9];
  #pragma unroll
  for(int i=0;i<9;i++) wv[i] = wdw[ch*9+i];
  float bv = bdw[ch];
  float* hdp = hd + (size_t)bc*L_;
  #pragma unroll
  for(int qq=0;qq<16;qq++){
    int lin = tid + qq*256; int h = lin>>6, w = lin&63;
    float acc = bv;
    #pragma unroll
    for(int ky=0;ky<3;ky++){
      int hh = h+ky-1; if(hh<0||hh>=64) continue;
      #pragma unroll
      for(int kx=0;kx<3;kx++){
        int ww = w+kx-1; if(ww<0||ww>=64) continue;
        acc = fmaf(wv[ky*3+kx], tin[hh][ww], acc);
      }
    }
    float s = siluf_(acc);
    hdp[lin] = s;
    tout[h][w] = s;
  }
  __syncthreads();
  float* hdtp = hdt + (size_t)bc*L_;
  #pragma unroll
  for(int qq=0;qq<16;qq++){
    int lin = tid + qq*256;
    hdtp[lin] = tout[lin&63][lin>>6];        // stride-65 LDS column read: conflict-free
  }
}

// ---------------------------------------------------------------------------
// K5: xdbl = xp . xs ; store xd4 (dt-rank proj), Bs, Cs. dt recomputed later.
// xd4 layout [bk][l][4]; Bs/Cs layout [bk][l][16].
__global__ __launch_bounds__(256) void k5_proj(
    const float* __restrict__ hd, const float* __restrict__ hdt,
    const float* __restrict__ xp, float* __restrict__ xd4,
    float* __restrict__ bsb, float* __restrict__ csb)
{
  int l = blockIdx.x*256 + threadIdx.x;
  int k = blockIdx.y, b = blockIdx.z;
  int pixv = (k<2)? l : (L_-1-l);
  const float* src = ((k&1)? hdt : hd) + (size_t)b*D_*L_ + pixv;
  const float* xpk = xp + k*36*D_;
  float xd[36];
  #pragma unroll
  for(int c=0;c<36;c++) xd[c]=0.f;
  for(int d=0;d<D_;d++){
    float u = src[(size_t)d*L_];
    #pragma unroll
    for(int c=0;c<36;c++) xd[c] = fmaf(xpk[c*D_+d], u, xd[c]);
  }
  int bk = b*K_+k;
  float4* xq = (float4*)(xd4 + ((size_t)bk*L_ + l)*4);
  *xq = make_float4(xd[0], xd[1], xd[2], xd[3]);
  float* bp = bsb + ((size_t)bk*L_ + l)*N_;
  float* cp = csb + ((size_t)bk*L_ + l)*N_;
  #pragma unroll
  for(int n=0;n<N_;n++){ bp[n]=xd[4+n]; cp[n]=xd[20+n]; }
}

// ---------------------------------------------------------------------------
// scan decode helper: t = ((b*K+k)*D+d)*NC + chunk
DEV void scan_decode(int t, int& b, int& k, int& d, int& chunk, int& bk){
  chunk = t & (NC_-1);
  int bkd = t >> 6;
  d = bkd & (D_-1);
  bk = bkd >> 7;
  k = bk & 3; b = bk >> 2;
}

// K6 phase 1: per-chunk composite (a = exp(A*Sum dt), b = local end state)
// lanes = chunks of one (b,k,d) row -> dtw/dtb/A loads are wave-uniform
__global__ __launch_bounds__(256) void k6_scan1(
    const float* __restrict__ xd4, const float* __restrict__ hd,
    const float* __restrict__ hdt, const float* __restrict__ bsb,
    const float* __restrict__ dtw, const float* __restrict__ dtb,
    const float* __restrict__ alog, float* __restrict__ ca, float* __restrict__ cb)
{
  int t = blockIdx.x*256 + threadIdx.x;
  int b,k,d,chunk,bk; scan_decode(t,b,k,d,chunk,bk);
  float A[N_];
  const float* al = alog + ((size_t)k*D_+d)*N_;
  #pragma unroll
  for(int n=0;n<N_;n++) A[n] = -__expf(al[n]);
  const float* wtd = dtw + ((size_t)k*D_+d)*R_;
  float w0=wtd[0], w1=wtd[1], w2=wtd[2], w3=wtd[3];
  float bdt = dtb[k*D_+d];
  const float4* xq = (const float4*)(xd4 + ((size_t)bk*L_ + chunk*CL_)*4);
  const float* srcp; int stp;
  {
    const float* base = ((k&1)? hdt : hd) + (size_t)b*D_*L_ + (size_t)d*L_;
    if(k<2){ srcp = base + chunk*CL_; stp = 1; }
    else   { srcp = base + (L_-1-chunk*CL_); stp = -1; }
  }
  const float* bp = bsb + ((size_t)bk*L_ + chunk*CL_)*N_;
  float h[N_];
  #pragma unroll
  for(int n=0;n<N_;n++) h[n]=0.f;
  float S=0.f;
  for(int i=0;i<CL_;i++){
    float4 xv = xq[i];
    float r = fmaf(xv.x,w0, fmaf(xv.y,w1, fmaf(xv.z,w2, fmaf(xv.w,w3, bdt))));
    float dt = softplusf_(r);
    float u = srcp[i*stp];
    S += dt;
    float du = dt*u;
    const float4* b4 = (const float4*)(bp + (size_t)i*N_);
    #pragma unroll
    for(int n4=0;n4<4;n4++){
      float4 bv = b4[n4];
      int n0=n4*4;
      h[n0+0] = fmaf(du, bv.x, h[n0+0]*__expf(dt*A[n0+0]));
      h[n0+1] = fmaf(du, bv.y, h[n0+1]*__expf(dt*A[n0+1]));
      h[n0+2] = fmaf(du, bv.z, h[n0+2]*__expf(dt*A[n0+2]));
      h[n0+3] = fmaf(du, bv.w, h[n0+3]*__expf(dt*A[n0+3]));
    }
  }
  float* cap = ca + (size_t)t*N_;
  float* cbp = cb + (size_t)t*N_;
  #pragma unroll
  for(int n=0;n<N_;n++){ cap[n] = __expf(S*A[n]); cbp[n] = h[n]; }
}

// K7 phase 2: sequential scan over chunk composites -> h0 per chunk
__global__ __launch_bounds__(256) void k7_scan2(
    const float* __restrict__ ca, const float* __restrict__ cb,
    float* __restrict__ h0)
{
  int t = blockIdx.x*256 + threadIdx.x;      // bkd*N + n, bkd < 2048
  int n = t & (N_-1); int bkd = t >> 4;
  size_t base = (size_t)bkd*NC_*N_ + n;
  float h=0.f;
  for(int c=0;c<NC_;c++){
    size_t idx = base + (size_t)c*N_;
    h0[idx] = h;
    h = fmaf(ca[idx], h, cb[idx]);
  }
}

// K8 phase 3: full scan with correct h0, emit y (+ dp*u) -> ys[b][k][d][l]
__global__ __launch_bounds__(256) void k8_scan3(
    const float* __restrict__ xd4, const float* __restrict__ hd,
    const float* __restrict__ hdt, const float* __restrict__ bsb,
    const float* __restrict__ csb, const float* __restrict__ h0b,
    const float* __restrict__ dtw, const float* __restrict__ dtb,
    const float* __restrict__ alog, const float* __restrict__ dp,
    float* __restrict__ ys)
{
  int t = blockIdx.x*256 + threadIdx.x;
  int b,k,d,chunk,bk; scan_decode(t,b,k,d,chunk,bk);
  float A[N_];
  const float* al = alog + ((size_t)k*D_+d)*N_;
  #pragma unroll
  for(int n=0;n<N_;n++) A[n] = -__expf(al[n]);
  const float* wtd = dtw + ((size_t)k*D_+d)*R_;
  float w0=wtd[0], w1=wtd[1], w2=wtd[2], w3=wtd[3];
  float bdt = dtb[k*D_+d];
  float h[N_];
  {
    const float4* h4 = (const float4*)(h0b + (size_t)t*N_);
    #pragma unroll
    for(int n4=0;n4<4;n4++){
      float4 hv = h4[n4];
      h[n4*4+0]=hv.x; h[n4*4+1]=hv.y; h[n4*4+2]=hv.z; h[n4*4+3]=hv.w;
    }
  }
  const float4* xq = (const float4*)(xd4 + ((size_t)bk*L_ + chunk*CL_)*4);
  const float* srcp; int stp;
  {
    const float* base = ((k&1)? hdt : hd) + (size_t)b*D_*L_ + (size_t)d*L_;
    if(k<2){ srcp = base + chunk*CL_; stp = 1; }
    else   { srcp = base + (L_-1-chunk*CL_); stp = -1; }
  }
  const float* bp = bsb + ((size_t)bk*L_ + chunk*CL_)*N_;
  const float* cp = csb + ((size_t)bk*L_ + chunk*CL_)*N_;
  float dpv = dp[k*D_+d];
  float* yp = ys + ((size_t)bk*D_+d)*L_ + chunk*CL_;
  for(int i=0;i<CL_;i++){
    float4 xv = xq[i];
    float r = fmaf(xv.x,w0, fmaf(xv.y,w1, fmaf(xv.z,w2, fmaf(xv.w,w3, bdt))));
    float dt = softplusf_(r);
    float u = srcp[i*stp];
    float du = dt*u;
    const float4* b4 = (const float4*)(bp + (size_t)i*N_);
    const float4* c4 = (const float4*)(cp + (size_t)i*N_);
    float y = 0.f;
    #pragma unroll
    for(int n4=0;n4<4;n4++){
      float4 bv = b4[n4]; float4 cv = c4[n4];
      int n0=n4*4;
      h[n0+0] = fmaf(du, bv.x, h[n0+0]*__expf(dt*A[n0+0])); y = fmaf(h[n0+0], cv.x, y);
      h[n0+1] = fmaf(du, bv.y, h[n0+1]*__expf(dt*A[n0+1])); y = fmaf(h[n0+1], cv.y, y);
      h[n0+2] = fmaf(du, bv.z, h[n0+2]*__expf(dt*A[n0+2])); y = fmaf(h[n0+2], cv.z, y);
      h[n0+3] = fmaf(du, bv.w, h[n0+3]*__expf(dt*A[n0+3])); y = fmaf(h[n0+3], cv.w, y);
    }
    y = fmaf(dpv, u, y);
    yp[i] = y;
  }
}

// ---------------------------------------------------------------------------
// K9a: combine 4 directions (+maps) then LN128  -> hn (B,128,H,W)
__global__ __launch_bounds__(64) void k9a_comb_ln(
    const float* __restrict__ ys, const float* __restrict__ g,
    const float* __restrict__ bb, float* __restrict__ hn)
{
  int t = blockIdx.x*64 + threadIdx.x;
  int b = t >> 12, pix = t & (L_-1);
  int pixT = ((pix&63)<<6) | (pix>>6);
  const float* y0 = ys + (size_t)(b*K_+0)*D_*L_;
  const float* y1 = ys + (size_t)(b*K_+1)*D_*L_;
  const float* y2 = ys + (size_t)(b*K_+2)*D_*L_;
  const float* y3 = ys + (size_t)(b*K_+3)*D_*L_;
  float* hb = hn + (size_t)b*D_*L_ + pix;
  float s=0.f;
  for(int d=0;d<D_;d++){
    float v = y0[(size_t)d*L_+pix] + y1[(size_t)d*L_+pixT]
            + y2[(size_t)d*L_+(L_-1-pix)] + y3[(size_t)d*L_+(L_-1-pixT)];
    hb[(size_t)d*L_] = v; s += v;
  }
  float m = s*(1.f/D_);
  float var=0.f;
  for(int d=0;d<D_;d++){ float dv = hb[(size_t)d*L_]-m; var += dv*dv; }
  var *= (1.f/D_);
  float rs = rsqrtf(var+EPS_);
  for(int d=0;d<D_;d++) hb[(size_t)d*L_] = (hb[(size_t)d*L_]-m)*rs*g[d] + bb[d];
}

// ---------------------------------------------------------------------------
// K9b: qg = conv1x1(hn, cv_ow) + cv_skip*skip; accumulate per-(b,ch) sums
__global__ __launch_bounds__(256) void k9b_ow(
    const float* __restrict__ hn, const float* __restrict__ w,
    const float* __restrict__ skip, const float* __restrict__ cskip,
    float* __restrict__ qg, float* __restrict__ meansum)
{
  int t = blockIdx.x*256 + threadIdx.x;      // ((b*4+grp)*L + pix)
  int pix = t & (L_-1); int bg = t >> 12; int b = bg >> 2; int grp = bg & 3;
  const float* hb = hn + (size_t)b*D_*L_ + pix;
  float acc[16];
  #pragma unroll
  for(int o=0;o<16;o++) acc[o]=0.f;
  for(int dd=0;dd<D_;dd++){
    float xv = hb[(size_t)dd*L_];
    #pragma unroll
    for(int oo=0;oo<16;oo++) acc[oo]=fmaf(w[(grp*16+oo)*D_+dd], xv, acc[oo]);
  }
  float csk = cskip[0];
  const float* sb = skip + (size_t)b*C_*L_ + pix;
  float* qb = qg + (size_t)b*C_*L_ + pix;
  #pragma unroll
  for(int oo=0;oo<16;oo++){
    int o = grp*16+oo;
    float v = acc[oo] + csk*sb[(size_t)o*L_];
    qb[(size_t)o*L_] = v;
    acc[oo] = v;
  }
  #pragma unroll
  for(int oo=0;oo<16;oo++){
    float v = acc[oo];
    #pragma unroll
    for(int off=32;off>0;off>>=1) v += __shfl_down(v, off, 64);
    if((threadIdx.x & 63)==0) atomicAdd(&meansum[b*C_ + grp*16+oo], v);
  }
}

// K10: ECA — conv1d(k=3) over channel means + sigmoid -> vsig (B,64)
__global__ __launch_bounds__(256) void k10_eca(
    const float* __restrict__ meansum, const float* __restrict__ ew,
    float* __restrict__ vsig)
{
  int t = threadIdx.x; if(t >= B_*C_) return;
  int b=t>>6, c=t&63;
  const float sc = 1.f/(float)L_;
  float ml = (c>0)?  meansum[b*C_+c-1]*sc : 0.f;
  float mc =         meansum[b*C_+c]*sc;
  float mr = (c<63)? meansum[b*C_+c+1]*sc : 0.f;
  float r = ew[0]*ml + ew[1]*mc + ew[2]*mr;
  vsig[t] = sigmoidf_(r);
}

// ---------------------------------------------------------------------------
// K11: x2 = v*qg + wgm*x  (on the fly); res = LN64(conv1x1(x2,pf_nw)+pf_nb)
__global__ __launch_bounds__(64) void k11_res(
    const float* __restrict__ qg, const float* __restrict__ xin,
    const float* __restrict__ vsig, const float* __restrict__ wgm,
    const float* __restrict__ w, const float* __restrict__ nb,
    const float* __restrict__ g, const float* __restrict__ bb,
    float* __restrict__ res)
{
  int t = blockIdx.x*64 + threadIdx.x;
  int b = t >> 12, pix = t & (L_-1);
  float wg = wgm[0];
  const float* qb = qg + (size_t)b*C_*L_ + pix;
  const float* xb = xin + (size_t)b*C_*L_ + pix;
  float acc[C_];
  #pragma unroll
  for(int o=0;o<C_;o++) acc[o]=nb[o];
  for(int c=0;c<C_;c++){
    float x2 = vsig[b*C_+c]*qb[(size_t)c*L_] + wg*xb[(size_t)c*L_];
    #pragma unroll
    for(int o=0;o<C_;o++) acc[o] = fmaf(w[o*C_+c], x2, acc[o]);
  }
  float m=0.f;
  #pragma unroll
  for(int o=0;o<C_;o++) m += acc[o];
  m *= (1.f/C_);
  float var=0.f;
  #pragma unroll
  for(int o=0;o<C_;o++){ float d=acc[o]-m; var += d*d; }
  var *= (1.f/C_);
  float rs = rsqrtf(var+EPS_);
  float* rb = res + (size_t)b*C_*L_ + pix;
  #pragma unroll
  for(int o=0;o<C_;o++) rb[(size_t)o*L_] = (acc[o]-m)*rs*g[o] + bb[o];
}

// ---------------------------------------------------------------------------
// K12: cascaded depthwise convs; one block per (b, c in 0..15), plane in LDS
DEV void conv_step(const float (*tin)[65], float (*tout)[65],
                   const float* __restrict__ wp, int ks, int pad, int dil,
                   float* __restrict__ gout, int tid)
{
  for(int qq=0;qq<16;qq++){
    int lin=tid+qq*256; int h=lin>>6, w=lin&63;
    float acc=0.f;
    for(int ky=0;ky<ks;ky++){
      int hh=h+ky*dil-pad; if(hh<0||hh>=64) continue;
      for(int kx=0;kx<ks;kx++){
        int ww=w+kx*dil-pad; if(ww<0||ww>=64) continue;
        acc = fmaf(wp[ky*ks+kx], tin[hh][ww], acc);
      }
    }
    tout[h][w]=acc; gout[lin]=acc;
  }
}

__global__ __launch_bounds__(256) void k12_cascade(
    const float* __restrict__ res, const float* __restrict__ d1,
    const float* __restrict__ d2, const float* __restrict__ d3,
    const float* __restrict__ d4, float* __restrict__ cat)
{
  __shared__ float ta[64][65];
  __shared__ float tb[64][65];
  int bc = blockIdx.x; int b = bc>>4; int c = bc&15;
  int tid = threadIdx.x;
  const float* rb = res + (size_t)b*C_*L_;
  float* catb = cat + (size_t)b*C_*L_;
  for(int qq=0;qq<16;qq++){ int lin=tid+qq*256; ta[lin>>6][lin&63] = rb[(size_t)c*L_+lin]; }
  __syncthreads();
  conv_step(ta, tb, d1+c*9, 3, 1, 1, catb + (size_t)c*L_, tid);
  __syncthreads();
  for(int qq=0;qq<16;qq++){ int lin=tid+qq*256; ta[lin>>6][lin&63] = tb[lin>>6][lin&63] + rb[(size_t)(16+c)*L_+lin]; }
  __syncthreads();
  conv_step(ta, tb, d2+c*49, 7, 3, 1, catb + (size_t)(16+c)*L_, tid);
  __syncthreads();
  for(int qq=0;qq<16;qq++){ int lin=tid+qq*256; ta[lin>>6][lin&63] = tb[lin>>6][lin&63] + rb[(size_t)(32+c)*L_+lin]; }
  __syncthreads();
  conv_step(ta, tb, d3+c*9, 3, 2, 2, catb + (size_t)(32+c)*L_, tid);
  __syncthreads();
  for(int qq=0;qq<16;qq++){ int lin=tid+qq*256; ta[lin>>6][lin&63] = tb[lin>>6][lin&63] + rb[(size_t)(48+c)*L_+lin]; }
  __syncthreads();
  conv_step(ta, tb, d4+c*9, 3, 3, 3, catb + (size_t)(48+c)*L_, tid);
}

// ---------------------------------------------------------------------------
// K13: out = silu( conv1x1( LN64(cat), pf_fw ) + pf_fb ) + pf_skip*res
__global__ __launch_bounds__(64) void k13_final(
    const float* __restrict__ cat, const float* __restrict__ res,
    const float* __restrict__ g, const float* __restrict__ bb,
    const float* __restrict__ fw, const float* __restrict__ fb,
    const float* __restrict__ pskip, float* __restrict__ out)
{
  int t = blockIdx.x*64 + threadIdx.x;
  int b = t >> 12, pix = t & (L_-1);
  const float* catb = cat + (size_t)b*C_*L_ + pix;
  float s=0.f;
  for(int c=0;c<C_;c++) s += catb[(size_t)c*L_];
  float m = s*(1.f/C_);
  float var=0.f;
  for(int c=0;c<C_;c++){ float d=catb[(size_t)c*L_]-m; var += d*d; }
  var *= (1.f/C_);
  float rs = rsqrtf(var+EPS_);
  float acc[C_];
  #pragma unroll
  for(int o=0;o<C_;o++) acc[o]=fb[o];
  for(int c=0;c<C_;c++){
    float cv = (catb[(size_t)c*L_]-m)*rs*g[c]+bb[c];
    #pragma unroll
    for(int o=0;o<C_;o++) acc[o] = fmaf(fw[o*C_+c], cv, acc[o]);
  }
  float ps = pskip[0];
  const float* rb = res + (size_t)b*C_*L_ + pix;
  float* ob = out + (size_t)b*C_*L_ + pix;
  #pragma unroll
  for(int o=0;o<C_;o++) ob[(size_t)o*L_] = siluf_(acc[o]) + ps*rb[(size_t)o*L_];
}

// ---------------------------------------------------------------------------
extern "C" void kernel_launch(void* const* d_in, const int* in_sizes, int n_in,
                              void* d_out, int out_size, void* d_ws, size_t ws_size,
                              hipStream_t stream)
{
  const float* x       = (const float*)d_in[0];
  const float* wt_dw   = (const float*)d_in[1];
  const float* wt_db   = (const float*)d_in[2];
  const float* wt_lng  = (const float*)d_in[3];
  const float* wt_lnb  = (const float*)d_in[4];
  const float* wt_ctw  = (const float*)d_in[5];
  const float* wt_ctb  = (const float*)d_in[6];
  const float* cv_inw  = (const float*)d_in[7];
  const float* cv_ln1g = (const float*)d_in[8];
  const float* cv_ln1b = (const float*)d_in[9];
  const float* cv_pw   = (const float*)d_in[10];
  const float* cv_dww  = (const float*)d_in[11];
  const float* cv_dwb  = (const float*)d_in[12];
  const float* ss_xp   = (const float*)d_in[13];
  const float* ss_dtw  = (const float*)d_in[14];
  const float* ss_dtb  = (const float*)d_in[15];
  const float* ss_alog = (const float*)d_in[16];
  const float* ss_d    = (const float*)d_in[17];
  const float* cv_ong  = (const float*)d_in[18];
  const float* cv_onb  = (const float*)d_in[19];
  const float* cv_ow   = (const float*)d_in[20];
  const float* cv_skip = (const float*)d_in[21];
  const float* eca_w   = (const float*)d_in[22];
  const float* wgm_skip= (const float*)d_in[23];
  const float* pf_nw   = (const float*)d_in[24];
  const float* pf_nb   = (const float*)d_in[25];
  const float* pf_lng  = (const float*)d_in[26];
  const float* pf_lnb  = (const float*)d_in[27];
  const float* pf_d1   = (const float*)d_in[28];
  const float* pf_d2   = (const float*)d_in[29];
  const float* pf_d3   = (const float*)d_in[30];
  const float* pf_d4   = (const float*)d_in[31];
  const float* pf_flng = (const float*)d_in[32];
  const float* pf_flnb = (const float*)d_in[33];
  const float* pf_fw   = (const float*)d_in[34];
  const float* pf_fb   = (const float*)d_in[35];
  const float* pf_skip = (const float*)d_in[36];
  float* outp = (float*)d_out;

  // ---- workspace layout with aliasing (total ~103 MB) ----
  float* ws = (float*)d_ws;
  size_t off = 0;
  float* q1   = ws+off; off += (size_t)B_*C4_*L_;        // 1 MB  k1->k2a
  float* q2   = ws+off;                                  // 4 MB  k2a->k2b
  float* qg   = q2;                                      //       k9b->k11 (aliases q2)
  off += (size_t)B_*C_*L_;
  float* skip = ws+off; off += (size_t)B_*C_*L_;         // 4 MB  k2b->k9b
  float* hp   = ws+off;                                  // 8 MB  k3->k4
  float* ca   = hp;                                      //       k6->k7 (aliases hp)
  off += (size_t)B_*D_*L_;
  float* hd   = ws+off;                                  // 8 MB  k4->k8
  float* res  = hd;                                      //       k11->k13 (aliases hd)
  off += (size_t)B_*D_*L_;
  float* hdt  = ws+off;                                  // 8 MB  k4->k8
  float* cat  = hdt;                                     //       k12->k13 (aliases hdt)
  off += (size_t)B_*D_*L_;
  float* xd4  = ws+off; off += (size_t)B_*K_*L_*R_;      // 1 MB  k5->k8
  float* bs   = ws+off; off += (size_t)B_*K_*L_*N_;      // 4 MB  k5->k8
  float* cs   = ws+off; off += (size_t)B_*K_*L_*N_;      // 4 MB  k5->k8
  float* cb   = ws+off;                                  // 8 MB  k6->k7
  float* hn   = cb;                                      //       k9a->k9b (aliases cb)
  off += (size_t)B_*K_*D_*NC_*N_;
  float* h0   = ws+off; off += (size_t)B_*K_*D_*NC_*N_;  // 8 MB  k7->k8
  float* ys   = ws+off; off += (size_t)B_*K_*D_*L_;      // 32 MB k8->k9a
  float* meansum = ws+off; off += 256;
  float* vsig    = ws+off; off += 256;
  (void)ws_size; (void)in_sizes; (void)n_in; (void)out_size;

  hipMemsetAsync(meansum, 0, B_*C_*sizeof(float), stream);

  k1_inln   <<<256, 64, 0, stream>>>(x, wt_dw, wt_db, wt_lng, wt_lnb, q1);
  k2a_dwtct <<<256, 256, 0, stream>>>(q1, wt_ctw, wt_ctb, q2);
  k2b_inconv_ln<<<256, 64, 0, stream>>>(q2, cv_inw, cv_ln1g, cv_ln1b, skip);
  k3_pw     <<<512, 256, 0, stream>>>(skip, cv_pw, hp);
  k4_dwsilu <<<512, 256, 0, stream>>>(hp, cv_dww, cv_dwb, hd, hdt);
  k5_proj   <<<dim3(16,4,4), 256, 0, stream>>>(hd, hdt, ss_xp, xd4, bs, cs);
  k6_scan1  <<<512, 256, 0, stream>>>(xd4, hd, hdt, bs, ss_dtw, ss_dtb, ss_alog, ca, cb);
  k7_scan2  <<<128, 256, 0, stream>>>(ca, cb, h0);
  k8_scan3  <<<512, 256, 0, stream>>>(xd4, hd, hdt, bs, cs, h0, ss_dtw, ss_dtb, ss_alog, ss_d, ys);
  k9a_comb_ln<<<256, 64, 0, stream>>>(ys, cv_ong, cv_onb, hn);
  k9b_ow    <<<256, 256, 0, stream>>>(hn, cv_ow, skip, cv_skip, qg, meansum);
  k10_eca   <<<1,   256, 0, stream>>>(meansum, eca_w, vsig);
  k11_res   <<<256, 64, 0, stream>>>(qg, x, vsig, wgm_skip, pf_nw, pf_nb, pf_lng, pf_lnb, res);
  k12_cascade<<<64, 256, 0, stream>>>(res, pf_d1, pf_d2, pf_d3, pf_d4, cat);
  k13_final <<<256, 64, 0, stream>>>(cat, res, pf_flng, pf_flnb, pf_fw, pf_fb, pf_skip, outp);
}

// Round 4
// 727.253 us; speedup vs baseline: 1.3392x; 1.3392x over previous
//
#include <hip/hip_runtime.h>
#include <cstdint>
#include <cstddef>

#define B_ 4
#define C_ 64
#define C4_ 16
#define D_ 128
#define H_ 64
#define W_ 64
#define L_ 4096
#define K_ 4
#define N_ 16
#define R_ 4
#define NC_ 64
#define CL_ 64
#define EPS_ 1e-6f

#define DEV __device__ __forceinline__

DEV float sigmoidf_(float x){ return 1.f/(1.f+__expf(-x)); }
DEV float siluf_(float x){ return x*sigmoidf_(x); }
// fast softplus: max(x,0) + log(1+exp(-|x|)); arg of log in [1,2] -> __logf fine
DEV float softplusf_(float x){ return fmaxf(x,0.f) + __logf(1.f+__expf(-fabsf(x))); }

// ---------------------------------------------------------------------------
// K1: q1 = LN16( conv1x1(x, wt_dw) + wt_db )   -> (B,16,H,W)
__global__ __launch_bounds__(64) void k1_inln(
    const float* __restrict__ x, const float* __restrict__ w,
    const float* __restrict__ bias, const float* __restrict__ g,
    const float* __restrict__ bb, float* __restrict__ q1)
{
  int t = blockIdx.x*64 + threadIdx.x;
  int b = t >> 12; int pix = t & (L_-1);
  const float* xb = x + (size_t)b*C_*L_ + pix;
  float acc[C4_];
  #pragma unroll
  for(int o=0;o<C4_;o++) acc[o] = bias[o];
  for(int c=0;c<C_;c++){
    float xv = xb[(size_t)c*L_];
    #pragma unroll
    for(int o=0;o<C4_;o++) acc[o] = fmaf(w[o*C_+c], xv, acc[o]);
  }
  float m=0.f;
  #pragma unroll
  for(int o=0;o<C4_;o++) m += acc[o];
  m *= (1.f/C4_);
  float var=0.f;
  #pragma unroll
  for(int o=0;o<C4_;o++){ float d=acc[o]-m; var += d*d; }
  var *= (1.f/C4_);
  float rs = rsqrtf(var+EPS_);
  float* qb = q1 + (size_t)b*C4_*L_ + pix;
  #pragma unroll
  for(int o=0;o<C4_;o++) qb[(size_t)o*L_] = (acc[o]-m)*rs*g[o] + bb[o];
}

// ---------------------------------------------------------------------------
// K2a: q2 = transposed-conv2x2( DWT_haar(q1) ) + ctb   -> (B,64,H,W)
__global__ __launch_bounds__(256) void k2a_dwtct(
    const float* __restrict__ q1, const float* __restrict__ ctw,
    const float* __restrict__ ctb, float* __restrict__ q2)
{
  int t = blockIdx.x*256 + threadIdx.x;      // ((b*4+quarter)*L + pix)
  int pix = t & (L_-1);
  int bq = t >> 12; int b = bq >> 2; int quarter = bq & 3;
  int y = pix >> 6, xw = pix & 63;
  int i = y >> 1, p = y & 1, j = xw >> 1, q = xw & 1;
  const float* qb = q1 + (size_t)b*C4_*L_;
  int p00 = (2*i)*W_ + 2*j;
  float ll[16], hl[16], lh[16], hh[16];
  #pragma unroll
  for(int c=0;c<16;c++){
    const float* pc = qb + (size_t)c*L_ + p00;
    float a = pc[0], bb2 = pc[1], cc = pc[W_], dd = pc[W_+1];
    ll[c] = (a+bb2+cc+dd)*0.5f;
    hl[c] = (bb2-a+dd-cc)*0.5f;
    lh[c] = (cc-a+dd-bb2)*0.5f;
    hh[c] = (a-bb2-cc+dd)*0.5f;
  }
  int pq = p*2+q;
  int obase = quarter*16;
  float* q2b = q2 + (size_t)b*C_*L_ + pix;
  #pragma unroll
  for(int oo=0;oo<16;oo++){
    int o = obase+oo;
    float acc = ctb[o];
    const float* wb = ctw + o*4 + pq;        // ctw[c][o][p][q], c-stride 256
    #pragma unroll
    for(int c=0;c<16;c++){
      acc = fmaf(ll[c], wb[c*256],       acc);
      acc = fmaf(hl[c], wb[(16+c)*256],  acc);
      acc = fmaf(lh[c], wb[(32+c)*256],  acc);
      acc = fmaf(hh[c], wb[(48+c)*256],  acc);
    }
    q2b[(size_t)o*L_] = acc;
  }
}

// ---------------------------------------------------------------------------
// K2b: skip = LN64( conv1x1(q2, cv_inw) )   -> (B,64,H,W)
__global__ __launch_bounds__(64) void k2b_inconv_ln(
    const float* __restrict__ q2, const float* __restrict__ w,
    const float* __restrict__ g, const float* __restrict__ bb,
    float* __restrict__ skip)
{
  int t = blockIdx.x*64 + threadIdx.x;
  int b = t >> 12; int pix = t & (L_-1);
  const float* qb = q2 + (size_t)b*C_*L_ + pix;
  float acc[C_];
  #pragma unroll
  for(int o=0;o<C_;o++) acc[o]=0.f;
  for(int c=0;c<C_;c++){
    float xv = qb[(size_t)c*L_];
    #pragma unroll
    for(int o=0;o<C_;o++) acc[o] = fmaf(w[o*C_+c], xv, acc[o]);
  }
  float m=0.f;
  #pragma unroll
  for(int o=0;o<C_;o++) m += acc[o];
  m *= (1.f/C_);
  float var=0.f;
  #pragma unroll
  for(int o=0;o<C_;o++){ float d=acc[o]-m; var += d*d; }
  var *= (1.f/C_);
  float rs = rsqrtf(var+EPS_);
  float* sb = skip + (size_t)b*C_*L_ + pix;
  #pragma unroll
  for(int o=0;o<C_;o++) sb[(size_t)o*L_] = (acc[o]-m)*rs*g[o] + bb[o];
}

// ---------------------------------------------------------------------------
// K3: hp = conv1x1(skip, cv_pw)   (64 -> 128)
__global__ __launch_bounds__(256) void k3_pw(
    const float* __restrict__ skip, const float* __restrict__ w,
    float* __restrict__ hp)
{
  int t = blockIdx.x*256 + threadIdx.x;      // ((b*8+grp)*L + pix)
  int pix = t & (L_-1);
  int bg = t >> 12; int b = bg >> 3; int grp = bg & 7;
  const float* sb = skip + (size_t)b*C_*L_ + pix;
  float acc[16];
  #pragma unroll
  for(int o=0;o<16;o++) acc[o]=0.f;
  for(int c=0;c<C_;c++){
    float xv = sb[(size_t)c*L_];
    #pragma unroll
    for(int oo=0;oo<16;oo++) acc[oo]=fmaf(w[(grp*16+oo)*C_+c], xv, acc[oo]);
  }
  float* hb = hp + (size_t)b*D_*L_ + (size_t)(grp*16)*L_ + pix;
  #pragma unroll
  for(int oo=0;oo<16;oo++) hb[(size_t)oo*L_] = acc[oo];
}

// ---------------------------------------------------------------------------
// K4: hd = silu(dw3x3(hp)+cv_dwb); hdt = spatial transpose of hd.
__global__ __launch_bounds__(256) void k4_dwsilu(
    const float* __restrict__ hp, const float* __restrict__ wdw,
    const float* __restrict__ bdw, float* __restrict__ hd,
    float* __restrict__ hdt)
{
  __shared__ float tin[64][65];
  __shared__ float tout[64][65];
  int bc = blockIdx.x;                       // b*D_ + ch
  int ch = bc & (D_-1);
  const float* plane = hp + (size_t)bc*L_;
  int tid = threadIdx.x;
  #pragma unroll
  for(int qq=0;qq<16;qq++){ int lin = tid + qq*256; tin[lin>>6][lin&63] = plane[lin]; }
  __syncthreads();
  float wv[9];
  #pragma unroll
  for(int i=0;i<9;i++) wv[i] = wdw[ch*9+i];
  float bv = bdw[ch];
  float* hdp = hd + (size_t)bc*L_;
  #pragma unroll
  for(int qq=0;qq<16;qq++){
    int lin = tid + qq*256; int h = lin>>6, w = lin&63;
    float acc = bv;
    #pragma unroll
    for(int ky=0;ky<3;ky++){
      int hh = h+ky-1; if(hh<0||hh>=64) continue;
      #pragma unroll
      for(int kx=0;kx<3;kx++){
        int ww = w+kx-1; if(ww<0||ww>=64) continue;
        acc = fmaf(wv[ky*3+kx], tin[hh][ww], acc);
      }
    }
    float s = siluf_(acc);
    hdp[lin] = s;
    tout[h][w] = s;
  }
  __syncthreads();
  float* hdtp = hdt + (size_t)bc*L_;
  #pragma unroll
  for(int qq=0;qq<16;qq++){
    int lin = tid + qq*256;
    hdtp[lin] = tout[lin&63][lin>>6];        // stride-65 LDS column read: conflict-free
  }
}

// ---------------------------------------------------------------------------
// K5: xdbl = xp . xs ; store xd4 (dt-rank proj), Bs, Cs.
// xd4 layout [bk][l][4]; Bs/Cs layout [bk][l][16]  (sequence-indexed).
__global__ __launch_bounds__(256) void k5_proj(
    const float* __restrict__ hd, const float* __restrict__ hdt,
    const float* __restrict__ xp, float* __restrict__ xd4,
    float* __restrict__ bsb, float* __restrict__ csb)
{
  int l = blockIdx.x*256 + threadIdx.x;
  int k = blockIdx.y, b = blockIdx.z;
  int pixv = (k<2)? l : (L_-1-l);
  const float* src = ((k&1)? hdt : hd) + (size_t)b*D_*L_ + pixv;
  const float* xpk = xp + k*36*D_;
  float xd[36];
  #pragma unroll
  for(int c=0;c<36;c++) xd[c]=0.f;
  for(int d=0;d<D_;d++){
    float u = src[(size_t)d*L_];
    #pragma unroll
    for(int c=0;c<36;c++) xd[c] = fmaf(xpk[c*D_+d], u, xd[c]);
  }
  int bk = b*K_+k;
  float4* xq = (float4*)(xd4 + ((size_t)bk*L_ + l)*4);
  *xq = make_float4(xd[0], xd[1], xd[2], xd[3]);
  float* bp = bsb + ((size_t)bk*L_ + l)*N_;
  float* cp = csb + ((size_t)bk*L_ + l)*N_;
  #pragma unroll
  for(int n=0;n<N_;n++){ bp[n]=xd[4+n]; cp[n]=xd[20+n]; }
}

// ---------------------------------------------------------------------------
// Scan block design: block = (chunk, k, b), 128 threads = d.
// u tile (128 d x 64 l) staged in LDS (stride-65: conflict-free column reads);
// Bs/Cs/xd4 staged once per block, broadcast-read. All global IO float4-coalesced.
// ca/cb/h0 layout: [bk][c][d][n].

// K6 phase 1: per-chunk composite (a = exp(A*Sum dt), b = local end state)
__global__ __launch_bounds__(128) void k6_scan1(
    const float* __restrict__ xd4, const float* __restrict__ hd,
    const float* __restrict__ hdt, const float* __restrict__ bsb,
    const float* __restrict__ dtw, const float* __restrict__ dtb,
    const float* __restrict__ alog, float* __restrict__ ca, float* __restrict__ cb)
{
  __shared__ float su[128][65];
  __shared__ float4 sb4[64][4];
  __shared__ float4 sx[64];
  int chunk = blockIdx.x, k = blockIdx.y, b = blockIdx.z;
  int d = threadIdx.x;
  int bk = b*K_ + k;
  bool rev = (k >= 2);
  int base_l = rev ? (63-chunk)*CL_ : chunk*CL_;
  const float* src = ((k&1)? hdt : hd) + (size_t)b*D_*L_;
  #pragma unroll
  for(int p=0;p<16;p++){
    int idx = p*128 + d; int row = idx >> 4, c4 = idx & 15;
    float4 v = *(const float4*)(src + (size_t)row*L_ + base_l + c4*4);
    su[row][c4*4+0]=v.x; su[row][c4*4+1]=v.y; su[row][c4*4+2]=v.z; su[row][c4*4+3]=v.w;
  }
  const float4* bsrc = (const float4*)(bsb + ((size_t)bk*L_ + chunk*CL_)*N_);
  #pragma unroll
  for(int p=0;p<2;p++){
    int idx = p*128 + d; int row = idx>>2, q = idx&3;
    sb4[row][q] = bsrc[idx];
  }
  {
    const float4* xsrc = (const float4*)(xd4 + ((size_t)bk*L_ + chunk*CL_)*4);
    if(d < 64) sx[d] = xsrc[d];
  }
  float A[N_];
  {
    const float* al = alog + ((size_t)k*D_+d)*N_;
    #pragma unroll
    for(int n=0;n<N_;n++) A[n] = -__expf(al[n]);
  }
  float4 wv = *(const float4*)(dtw + ((size_t)k*D_+d)*R_);
  float bdt = dtb[k*D_+d];
  __syncthreads();
  float h[N_];
  #pragma unroll
  for(int n=0;n<N_;n++) h[n]=0.f;
  float S=0.f;
  for(int i=0;i<CL_;i++){
    int jj = rev ? (CL_-1-i) : i;
    float4 xv = sx[i];
    float r = fmaf(xv.x,wv.x, fmaf(xv.y,wv.y, fmaf(xv.z,wv.z, fmaf(xv.w,wv.w, bdt))));
    float dt = softplusf_(r);
    float u = su[d][jj];
    S += dt;
    float du = dt*u;
    #pragma unroll
    for(int n4=0;n4<4;n4++){
      float4 bv = sb4[i][n4];
      int n0=n4*4;
      h[n0+0] = fmaf(du, bv.x, h[n0+0]*__expf(dt*A[n0+0]));
      h[n0+1] = fmaf(du, bv.y, h[n0+1]*__expf(dt*A[n0+1]));
      h[n0+2] = fmaf(du, bv.z, h[n0+2]*__expf(dt*A[n0+2]));
      h[n0+3] = fmaf(du, bv.w, h[n0+3]*__expf(dt*A[n0+3]));
    }
  }
  size_t obase = (((size_t)bk*NC_ + chunk)*D_ + d)*N_;
  float4* cap = (float4*)(ca + obase);
  float4* cbp = (float4*)(cb + obase);
  #pragma unroll
  for(int n4=0;n4<4;n4++){
    int n0=n4*4;
    cap[n4] = make_float4(__expf(S*A[n0]), __expf(S*A[n0+1]), __expf(S*A[n0+2]), __expf(S*A[n0+3]));
    cbp[n4] = make_float4(h[n0], h[n0+1], h[n0+2], h[n0+3]);
  }
}

// K7 phase 2: sequential scan over chunk composites -> h0 per chunk
// thread = (bk, d, n); all loads/stores coalesced in [bk][c][d][n] layout
__global__ __launch_bounds__(256) void k7_scan2(
    const float* __restrict__ ca, const float* __restrict__ cb,
    float* __restrict__ h0)
{
  int t = blockIdx.x*256 + threadIdx.x;      // bk*2048 + d*16 + n
  int bk = t >> 11; int dn = t & 2047;
  size_t base = (size_t)bk*NC_*D_*N_ + dn;
  float h=0.f;
  for(int c=0;c<NC_;c++){
    size_t idx = base + (size_t)c*D_*N_;
    h0[idx] = h;
    h = fmaf(ca[idx], h, cb[idx]);
  }
}

// K8 phase 3: full scan with correct h0, emit y (+ dp*u) -> ys[bk][d][l] (seq-indexed)
__global__ __launch_bounds__(128) void k8_scan3(
    const float* __restrict__ xd4, const float* __restrict__ hd,
    const float* __restrict__ hdt, const float* __restrict__ bsb,
    const float* __restrict__ csb, const float* __restrict__ h0b,
    const float* __restrict__ dtw, const float* __restrict__ dtb,
    const float* __restrict__ alog, const float* __restrict__ dp,
    float* __restrict__ ys)
{
  __shared__ float su[128][65];
  __shared__ float4 sb4[64][4];
  __shared__ float4 sc4[64][4];
  __shared__ float4 sx[64];
  int chunk = blockIdx.x, k = blockIdx.y, b = blockIdx.z;
  int d = threadIdx.x;
  int bk = b*K_ + k;
  bool rev = (k >= 2);
  int base_l = rev ? (63-chunk)*CL_ : chunk*CL_;
  const float* src = ((k&1)? hdt : hd) + (size_t)b*D_*L_;
  #pragma unroll
  for(int p=0;p<16;p++){
    int idx = p*128 + d; int row = idx >> 4, c4 = idx & 15;
    float4 v = *(const float4*)(src + (size_t)row*L_ + base_l + c4*4);
    su[row][c4*4+0]=v.x; su[row][c4*4+1]=v.y; su[row][c4*4+2]=v.z; su[row][c4*4+3]=v.w;
  }
  const float4* bsrc = (const float4*)(bsb + ((size_t)bk*L_ + chunk*CL_)*N_);
  const float4* csrc = (const float4*)(csb + ((size_t)bk*L_ + chunk*CL_)*N_);
  #pragma unroll
  for(int p=0;p<2;p++){
    int idx = p*128 + d; int row = idx>>2, q = idx&3;
    sb4[row][q] = bsrc[idx];
    sc4[row][q] = csrc[idx];
  }
  {
    const float4* xsrc = (const float4*)(xd4 + ((size_t)bk*L_ + chunk*CL_)*4);
    if(d < 64) sx[d] = xsrc[d];
  }
  float A[N_];
  {
    const float* al = alog + ((size_t)k*D_+d)*N_;
    #pragma unroll
    for(int n=0;n<N_;n++) A[n] = -__expf(al[n]);
  }
  float4 wv = *(const float4*)(dtw + ((size_t)k*D_+d)*R_);
  float bdt = dtb[k*D_+d];
  float dpv = dp[k*D_+d];
  float h[N_];
  {
    size_t hbase = (((size_t)bk*NC_ + chunk)*D_ + d)*N_;
    const float4* h4 = (const float4*)(h0b + hbase);
    #pragma unroll
    for(int n4=0;n4<4;n4++){
      float4 hv = h4[n4];
      h[n4*4+0]=hv.x; h[n4*4+1]=hv.y; h[n4*4+2]=hv.z; h[n4*4+3]=hv.w;
    }
  }
  __syncthreads();
  for(int i=0;i<CL_;i++){
    int jj = rev ? (CL_-1-i) : i;
    float4 xv = sx[i];
    float r = fmaf(xv.x,wv.x, fmaf(xv.y,wv.y, fmaf(xv.z,wv.z, fmaf(xv.w,wv.w, bdt))));
    float dt = softplusf_(r);
    float u = su[d][jj];
    float du = dt*u;
    float y = 0.f;
    #pragma unroll
    for(int n4=0;n4<4;n4++){
      float4 bv = sb4[i][n4];
      float4 cv = sc4[i][n4];
      int n0=n4*4;
      h[n0+0] = fmaf(du, bv.x, h[n0+0]*__expf(dt*A[n0+0])); y = fmaf(h[n0+0], cv.x, y);
      h[n0+1] = fmaf(du, bv.y, h[n0+1]*__expf(dt*A[n0+1])); y = fmaf(h[n0+1], cv.y, y);
      h[n0+2] = fmaf(du, bv.z, h[n0+2]*__expf(dt*A[n0+2])); y = fmaf(h[n0+2], cv.z, y);
      h[n0+3] = fmaf(du, bv.w, h[n0+3]*__expf(dt*A[n0+3])); y = fmaf(h[n0+3], cv.w, y);
    }
    y = fmaf(dpv, u, y);
    su[d][jj] = y;                            // overwrite consumed u slot
  }
  __syncthreads();
  // coalesced copy-out: ys[(bk*D+row)*L + chunk*64 + m] = su[row][rev ? 63-m : m]
  #pragma unroll
  for(int p=0;p<16;p++){
    int idx = p*128 + d; int row = idx >> 4, c4 = idx & 15;
    int m0 = c4*4;
    float4 v;
    if(rev) v = make_float4(su[row][63-m0], su[row][62-m0], su[row][61-m0], su[row][60-m0]);
    else    v = make_float4(su[row][m0], su[row][m0+1], su[row][m0+2], su[row][m0+3]);
    *(float4*)(ys + ((size_t)bk*D_ + row)*L_ + chunk*CL_ + m0) = v;
  }
}

// ---------------------------------------------------------------------------
// K9a: combine 4 directions (+maps) then LN128  -> hn (B,128,H,W). Single pass, regs.
__global__ __launch_bounds__(64) void k9a_comb_ln(
    const float* __restrict__ ys, const float* __restrict__ g,
    const float* __restrict__ bb, float* __restrict__ hn)
{
  int t = blockIdx.x*64 + threadIdx.x;
  int b = t >> 12, pix = t & (L_-1);
  int pixT = ((pix&63)<<6) | (pix>>6);
  const float* y0 = ys + (size_t)(b*K_+0)*D_*L_;
  const float* y1 = ys + (size_t)(b*K_+1)*D_*L_;
  const float* y2 = ys + (size_t)(b*K_+2)*D_*L_;
  const float* y3 = ys + (size_t)(b*K_+3)*D_*L_;
  float v[D_];
  float s=0.f;
  #pragma unroll
  for(int dd=0;dd<D_;dd++){
    float vv = y0[(size_t)dd*L_+pix] + y1[(size_t)dd*L_+pixT]
             + y2[(size_t)dd*L_+(L_-1-pix)] + y3[(size_t)dd*L_+(L_-1-pixT)];
    v[dd]=vv; s += vv;
  }
  float m = s*(1.f/D_);
  float var=0.f;
  #pragma unroll
  for(int dd=0;dd<D_;dd++){ float dv = v[dd]-m; var = fmaf(dv,dv,var); }
  float rs = rsqrtf(var*(1.f/D_)+EPS_);
  float* hb = hn + (size_t)b*D_*L_ + pix;
  #pragma unroll
  for(int dd=0;dd<D_;dd++) hb[(size_t)dd*L_] = (v[dd]-m)*rs*g[dd] + bb[dd];
}

// ---------------------------------------------------------------------------
// K9b: qg = conv1x1(hn, cv_ow) + cv_skip*skip; accumulate per-(b,ch) sums
__global__ __launch_bounds__(256) void k9b_ow(
    const float* __restrict__ hn, const float* __restrict__ w,
    const float* __restrict__ skip, const float* __restrict__ cskip,
    float* __restrict__ qg, float* __restrict__ meansum)
{
  int t = blockIdx.x*256 + threadIdx.x;      // ((b*4+grp)*L + pix)
  int pix = t & (L_-1); int bg = t >> 12; int b = bg >> 2; int grp = bg & 3;
  const float* hb = hn + (size_t)b*D_*L_ + pix;
  float acc[16];
  #pragma unroll
  for(int o=0;o<16;o++) acc[o]=0.f;
  for(int dd=0;dd<D_;dd++){
    float xv = hb[(size_t)dd*L_];
    #pragma unroll
    for(int oo=0;oo<16;oo++) acc[oo]=fmaf(w[(grp*16+oo)*D_+dd], xv, acc[oo]);
  }
  float csk = cskip[0];
  const float* sb = skip + (size_t)b*C_*L_ + pix;
  float* qb = qg + (size_t)b*C_*L_ + pix;
  #pragma unroll
  for(int oo=0;oo<16;oo++){
    int o = grp*16+oo;
    float v = acc[oo] + csk*sb[(size_t)o*L_];
    qb[(size_t)o*L_] = v;
    acc[oo] = v;
  }
  #pragma unroll
  for(int oo=0;oo<16;oo++){
    float v = acc[oo];
    #pragma unroll
    for(int off=32;off>0;off>>=1) v += __shfl_down(v, off, 64);
    if((threadIdx.x & 63)==0) atomicAdd(&meansum[b*C_ + grp*16+oo], v);
  }
}

// K10: ECA — conv1d(k=3) over channel means + sigmoid -> vsig (B,64)
__global__ __launch_bounds__(256) void k10_eca(
    const float* __restrict__ meansum, const float* __restrict__ ew,
    float* __restrict__ vsig)
{
  int t = threadIdx.x; if(t >= B_*C_) return;
  int b=t>>6, c=t&63;
  const float sc = 1.f/(float)L_;
  float ml = (c>0)?  meansum[b*C_+c-1]*sc : 0.f;
  float mc =         meansum[b*C_+c]*sc;
  float mr = (c<63)? meansum[b*C_+c+1]*sc : 0.f;
  float r = ew[0]*ml + ew[1]*mc + ew[2]*mr;
  vsig[t] = sigmoidf_(r);
}

// ---------------------------------------------------------------------------
// K11: x2 = v*qg + wgm*x  (on the fly); res = LN64(conv1x1(x2,pf_nw)+pf_nb)
__global__ __launch_bounds__(64) void k11_res(
    const float* __restrict__ qg, const float* __restrict__ xin,
    const float* __restrict__ vsig, const float* __restrict__ wgm,
    const float* __restrict__ w, const float* __restrict__ nb,
    const float* __restrict__ g, const float* __restrict__ bb,
    float* __restrict__ res)
{
  int t = blockIdx.x*64 + threadIdx.x;
  int b = t >> 12, pix = t & (L_-1);
  float wg = wgm[0];
  const float* qb = qg + (size_t)b*C_*L_ + pix;
  const float* xb = xin + (size_t)b*C_*L_ + pix;
  float acc[C_];
  #pragma unroll
  for(int o=0;o<C_;o++) acc[o]=nb[o];
  for(int c=0;c<C_;c++){
    float x2 = vsig[b*C_+c]*qb[(size_t)c*L_] + wg*xb[(size_t)c*L_];
    #pragma unroll
    for(int o=0;o<C_;o++) acc[o] = fmaf(w[o*C_+c], x2, acc[o]);
  }
  float m=0.f;
  #pragma unroll
  for(int o=0;o<C_;o++) m += acc[o];
  m *= (1.f/C_);
  float var=0.f;
  #pragma unroll
  for(int o=0;o<C_;o++){ float d=acc[o]-m; var += d*d; }
  var *= (1.f/C_);
  float rs = rsqrtf(var+EPS_);
  float* rb = res + (size_t)b*C_*L_ + pix;
  #pragma unroll
  for(int o=0;o<C_;o++) rb[(size_t)o*L_] = (acc[o]-m)*rs*g[o] + bb[o];
}

// ---------------------------------------------------------------------------
// K12: cascaded depthwise convs; one block per (b, c in 0..15), plane in LDS
DEV void conv_step(const float (*tin)[65], float (*tout)[65],
                   const float* __restrict__ wp, int ks, int pad, int dil,
                   float* __restrict__ gout, int tid)
{
  for(int qq=0;qq<16;qq++){
    int lin=tid+qq*256; int h=lin>>6, w=lin&63;
    float acc=0.f;
    for(int ky=0;ky<ks;ky++){
      int hh=h+ky*dil-pad; if(hh<0||hh>=64) continue;
      for(int kx=0;kx<ks;kx++){
        int ww=w+kx*dil-pad; if(ww<0||ww>=64) continue;
        acc = fmaf(wp[ky*ks+kx], tin[hh][ww], acc);
      }
    }
    tout[h][w]=acc; gout[lin]=acc;
  }
}

__global__ __launch_bounds__(256) void k12_cascade(
    const float* __restrict__ res, const float* __restrict__ d1,
    const float* __restrict__ d2, const float* __restrict__ d3,
    const float* __restrict__ d4, float* __restrict__ cat)
{
  __shared__ float ta[64][65];
  __shared__ float tb[64][65];
  int bc = blockIdx.x; int b = bc>>4; int c = bc&15;
  int tid = threadIdx.x;
  const float* rb = res + (size_t)b*C_*L_;
  float* catb = cat + (size_t)b*C_*L_;
  for(int qq=0;qq<16;qq++){ int lin=tid+qq*256; ta[lin>>6][lin&63] = rb[(size_t)c*L_+lin]; }
  __syncthreads();
  conv_step(ta, tb, d1+c*9, 3, 1, 1, catb + (size_t)c*L_, tid);
  __syncthreads();
  for(int qq=0;qq<16;qq++){ int lin=tid+qq*256; ta[lin>>6][lin&63] = tb[lin>>6][lin&63] + rb[(size_t)(16+c)*L_+lin]; }
  __syncthreads();
  conv_step(ta, tb, d2+c*49, 7, 3, 1, catb + (size_t)(16+c)*L_, tid);
  __syncthreads();
  for(int qq=0;qq<16;qq++){ int lin=tid+qq*256; ta[lin>>6][lin&63] = tb[lin>>6][lin&63] + rb[(size_t)(32+c)*L_+lin]; }
  __syncthreads();
  conv_step(ta, tb, d3+c*9, 3, 2, 2, catb + (size_t)(32+c)*L_, tid);
  __syncthreads();
  for(int qq=0;qq<16;qq++){ int lin=tid+qq*256; ta[lin>>6][lin&63] = tb[lin>>6][lin&63] + rb[(size_t)(48+c)*L_+lin]; }
  __syncthreads();
  conv_step(ta, tb, d4+c*9, 3, 3, 3, catb + (size_t)(48+c)*L_, tid);
}

// ---------------------------------------------------------------------------
// K13: out = silu( conv1x1( LN64(cat), pf_fw ) + pf_fb ) + pf_skip*res
__global__ __launch_bounds__(64) void k13_final(
    const float* __restrict__ cat, const float* __restrict__ res,
    const float* __restrict__ g, const float* __restrict__ bb,
    const float* __restrict__ fw, const float* __restrict__ fb,
    const float* __restrict__ pskip, float* __restrict__ out)
{
  int t = blockIdx.x*64 + threadIdx.x;
  int b = t >> 12, pix = t & (L_-1);
  const float* catb = cat + (size_t)b*C_*L_ + pix;
  float s=0.f;
  for(int c=0;c<C_;c++) s += catb[(size_t)c*L_];
  float m = s*(1.f/C_);
  float var=0.f;
  for(int c=0;c<C_;c++){ float d=catb[(size_t)c*L_]-m; var += d*d; }
  var *= (1.f/C_);
  float rs = rsqrtf(var+EPS_);
  float acc[C_];
  #pragma unroll
  for(int o=0;o<C_;o++) acc[o]=fb[o];
  for(int c=0;c<C_;c++){
    float cv = (catb[(size_t)c*L_]-m)*rs*g[c]+bb[c];
    #pragma unroll
    for(int o=0;o<C_;o++) acc[o] = fmaf(fw[o*C_+c], cv, acc[o]);
  }
  float ps = pskip[0];
  const float* rb = res + (size_t)b*C_*L_ + pix;
  float* ob = out + (size_t)b*C_*L_ + pix;
  #pragma unroll
  for(int o=0;o<C_;o++) ob[(size_t)o*L_] = siluf_(acc[o]) + ps*rb[(size_t)o*L_];
}

// ---------------------------------------------------------------------------
extern "C" void kernel_launch(void* const* d_in, const int* in_sizes, int n_in,
                              void* d_out, int out_size, void* d_ws, size_t ws_size,
                              hipStream_t stream)
{
  const float* x       = (const float*)d_in[0];
  const float* wt_dw   = (const float*)d_in[1];
  const float* wt_db   = (const float*)d_in[2];
  const float* wt_lng  = (const float*)d_in[3];
  const float* wt_lnb  = (const float*)d_in[4];
  const float* wt_ctw  = (const float*)d_in[5];
  const float* wt_ctb  = (const float*)d_in[6];
  const float* cv_inw  = (const float*)d_in[7];
  const float* cv_ln1g = (const float*)d_in[8];
  const float* cv_ln1b = (const float*)d_in[9];
  const float* cv_pw   = (const float*)d_in[10];
  const float* cv_dww  = (const float*)d_in[11];
  const float* cv_dwb  = (const float*)d_in[12];
  const float* ss_xp   = (const float*)d_in[13];
  const float* ss_dtw  = (const float*)d_in[14];
  const float* ss_dtb  = (const float*)d_in[15];
  const float* ss_alog = (const float*)d_in[16];
  const float* ss_d    = (const float*)d_in[17];
  const float* cv_ong  = (const float*)d_in[18];
  const float* cv_onb  = (const float*)d_in[19];
  const float* cv_ow   = (const float*)d_in[20];
  const float* cv_skip = (const float*)d_in[21];
  const float* eca_w   = (const float*)d_in[22];
  const float* wgm_skip= (const float*)d_in[23];
  const float* pf_nw   = (const float*)d_in[24];
  const float* pf_nb   = (const float*)d_in[25];
  const float* pf_lng  = (const float*)d_in[26];
  const float* pf_lnb  = (const float*)d_in[27];
  const float* pf_d1   = (const float*)d_in[28];
  const float* pf_d2   = (const float*)d_in[29];
  const float* pf_d3   = (const float*)d_in[30];
  const float* pf_d4   = (const float*)d_in[31];
  const float* pf_flng = (const float*)d_in[32];
  const float* pf_flnb = (const float*)d_in[33];
  const float* pf_fw   = (const float*)d_in[34];
  const float* pf_fb   = (const float*)d_in[35];
  const float* pf_skip = (const float*)d_in[36];
  float* outp = (float*)d_out;

  // ---- workspace layout with aliasing ----
  float* ws = (float*)d_ws;
  size_t off = 0;
  float* q1   = ws+off; off += (size_t)B_*C4_*L_;        // 1 MB  k1->k2a
  float* q2   = ws+off;                                  // 4 MB  k2a->k2b
  float* qg   = q2;                                      //       k9b->k11 (aliases q2)
  off += (size_t)B_*C_*L_;
  float* skip = ws+off; off += (size_t)B_*C_*L_;         // 4 MB  k2b->k9b
  float* hp   = ws+off;                                  // 8 MB  k3->k4
  float* ca   = hp;                                      //       k6->k7 (aliases hp)
  off += (size_t)B_*D_*L_;
  float* hd   = ws+off;                                  // 8 MB  k4->k8
  float* res  = hd;                                      //       k11->k13 (aliases hd)
  off += (size_t)B_*D_*L_;
  float* hdt  = ws+off;                                  // 8 MB  k4->k8
  float* cat  = hdt;                                     //       k12->k13 (aliases hdt)
  off += (size_t)B_*D_*L_;
  float* xd4  = ws+off; off += (size_t)B_*K_*L_*R_;      // 1 MB  k5->k8
  float* bs   = ws+off; off += (size_t)B_*K_*L_*N_;      // 4 MB  k5->k8
  float* cs   = ws+off; off += (size_t)B_*K_*L_*N_;      // 4 MB  k5->k8
  float* cb   = ws+off;                                  // 8 MB  k6->k7
  float* hn   = cb;                                      //       k9a->k9b (aliases cb)
  off += (size_t)B_*K_*D_*NC_*N_;
  float* h0   = ws+off; off += (size_t)B_*K_*D_*NC_*N_;  // 8 MB  k7->k8
  float* ys   = ws+off; off += (size_t)B_*K_*D_*L_;      // 32 MB k8->k9a
  float* meansum = ws+off; off += 256;
  float* vsig    = ws+off; off += 256;
  (void)ws_size; (void)in_sizes; (void)n_in; (void)out_size;

  hipMemsetAsync(meansum, 0, B_*C_*sizeof(float), stream);

  k1_inln   <<<256, 64, 0, stream>>>(x, wt_dw, wt_db, wt_lng, wt_lnb, q1);
  k2a_dwtct <<<256, 256, 0, stream>>>(q1, wt_ctw, wt_ctb, q2);
  k2b_inconv_ln<<<256, 64, 0, stream>>>(q2, cv_inw, cv_ln1g, cv_ln1b, skip);
  k3_pw     <<<512, 256, 0, stream>>>(skip, cv_pw, hp);
  k4_dwsilu <<<512, 256, 0, stream>>>(hp, cv_dww, cv_dwb, hd, hdt);
  k5_proj   <<<dim3(16,4,4), 256, 0, stream>>>(hd, hdt, ss_xp, xd4, bs, cs);
  k6_scan1  <<<dim3(NC_,K_,B_), 128, 0, stream>>>(xd4, hd, hdt, bs, ss_dtw, ss_dtb, ss_alog, ca, cb);
  k7_scan2  <<<128, 256, 0, stream>>>(ca, cb, h0);
  k8_scan3  <<<dim3(NC_,K_,B_), 128, 0, stream>>>(xd4, hd, hdt, bs, cs, h0, ss_dtw, ss_dtb, ss_alog, ss_d, ys);
  k9a_comb_ln<<<256, 64, 0, stream>>>(ys, cv_ong, cv_onb, hn);
  k9b_ow    <<<256, 256, 0, stream>>>(hn, cv_ow, skip, cv_skip, qg, meansum);
  k10_eca   <<<1,   256, 0, stream>>>(meansum, eca_w, vsig);
  k11_res   <<<256, 64, 0, stream>>>(qg, x, vsig, wgm_skip, pf_nw, pf_nb, pf_lng, pf_lnb, res);
  k12_cascade<<<64, 256, 0, stream>>>(res, pf_d1, pf_d2, pf_d3, pf_d4, cat);
  k13_final <<<256, 64, 0, stream>>>(cat, res, pf_flng, pf_flnb, pf_fw, pf_fb, pf_skip, outp);
}

// Round 5
// 613.962 us; speedup vs baseline: 1.5863x; 1.1845x over previous
//
#include <hip/hip_runtime.h>
#include <cstdint>
#include <cstddef>

#define B_ 4
#define C_ 64
#define C4_ 16
#define D_ 128
#define H_ 64
#define W_ 64
#define L_ 4096
#define K_ 4
#define N_ 16
#define R_ 4
#define NC_ 64
#define CL_ 64
#define EPS_ 1e-6f

#define DEV __device__ __forceinline__

DEV float sigmoidf_(float x){ return 1.f/(1.f+__expf(-x)); }
DEV float siluf_(float x){ return x*sigmoidf_(x); }
// fast softplus: max(x,0) + log(1+exp(-|x|)); arg of log in [1,2] -> __logf fine
DEV float softplusf_(float x){ return fmaxf(x,0.f) + __logf(1.f+__expf(-fabsf(x))); }

// ---------------------------------------------------------------------------
// K1: q1 = LN16( conv1x1(x, wt_dw) + wt_db )   -> (B,16,H,W)
__global__ __launch_bounds__(64) void k1_inln(
    const float* __restrict__ x, const float* __restrict__ w,
    const float* __restrict__ bias, const float* __restrict__ g,
    const float* __restrict__ bb, float* __restrict__ q1)
{
  int t = blockIdx.x*64 + threadIdx.x;
  int b = t >> 12; int pix = t & (L_-1);
  const float* xb = x + (size_t)b*C_*L_ + pix;
  float acc[C4_];
  #pragma unroll
  for(int o=0;o<C4_;o++) acc[o] = bias[o];
  for(int c=0;c<C_;c++){
    float xv = xb[(size_t)c*L_];
    #pragma unroll
    for(int o=0;o<C4_;o++) acc[o] = fmaf(w[o*C_+c], xv, acc[o]);
  }
  float m=0.f;
  #pragma unroll
  for(int o=0;o<C4_;o++) m += acc[o];
  m *= (1.f/C4_);
  float var=0.f;
  #pragma unroll
  for(int o=0;o<C4_;o++){ float d=acc[o]-m; var += d*d; }
  var *= (1.f/C4_);
  float rs = rsqrtf(var+EPS_);
  float* qb = q1 + (size_t)b*C4_*L_ + pix;
  #pragma unroll
  for(int o=0;o<C4_;o++) qb[(size_t)o*L_] = (acc[o]-m)*rs*g[o] + bb[o];
}

// ---------------------------------------------------------------------------
// K2a: q2 = transposed-conv2x2( DWT_haar(q1) ) + ctb   -> (B,64,H,W)
__global__ __launch_bounds__(256) void k2a_dwtct(
    const float* __restrict__ q1, const float* __restrict__ ctw,
    const float* __restrict__ ctb, float* __restrict__ q2)
{
  int t = blockIdx.x*256 + threadIdx.x;      // ((b*4+quarter)*L + pix)
  int pix = t & (L_-1);
  int bq = t >> 12; int b = bq >> 2; int quarter = bq & 3;
  int y = pix >> 6, xw = pix & 63;
  int i = y >> 1, p = y & 1, j = xw >> 1, q = xw & 1;
  const float* qb = q1 + (size_t)b*C4_*L_;
  int p00 = (2*i)*W_ + 2*j;
  float ll[16], hl[16], lh[16], hh[16];
  #pragma unroll
  for(int c=0;c<16;c++){
    const float* pc = qb + (size_t)c*L_ + p00;
    float a = pc[0], bb2 = pc[1], cc = pc[W_], dd = pc[W_+1];
    ll[c] = (a+bb2+cc+dd)*0.5f;
    hl[c] = (bb2-a+dd-cc)*0.5f;
    lh[c] = (cc-a+dd-bb2)*0.5f;
    hh[c] = (a-bb2-cc+dd)*0.5f;
  }
  int pq = p*2+q;
  int obase = quarter*16;
  float* q2b = q2 + (size_t)b*C_*L_ + pix;
  #pragma unroll
  for(int oo=0;oo<16;oo++){
    int o = obase+oo;
    float acc = ctb[o];
    const float* wb = ctw + o*4 + pq;        // ctw[c][o][p][q], c-stride 256
    #pragma unroll
    for(int c=0;c<16;c++){
      acc = fmaf(ll[c], wb[c*256],       acc);
      acc = fmaf(hl[c], wb[(16+c)*256],  acc);
      acc = fmaf(lh[c], wb[(32+c)*256],  acc);
      acc = fmaf(hh[c], wb[(48+c)*256],  acc);
    }
    q2b[(size_t)o*L_] = acc;
  }
}

// ---------------------------------------------------------------------------
// K2b: skip = LN64( conv1x1(q2, cv_inw) )   -> (B,64,H,W)
__global__ __launch_bounds__(64) void k2b_inconv_ln(
    const float* __restrict__ q2, const float* __restrict__ w,
    const float* __restrict__ g, const float* __restrict__ bb,
    float* __restrict__ skip)
{
  int t = blockIdx.x*64 + threadIdx.x;
  int b = t >> 12; int pix = t & (L_-1);
  const float* qb = q2 + (size_t)b*C_*L_ + pix;
  float acc[C_];
  #pragma unroll
  for(int o=0;o<C_;o++) acc[o]=0.f;
  for(int c=0;c<C_;c++){
    float xv = qb[(size_t)c*L_];
    #pragma unroll
    for(int o=0;o<C_;o++) acc[o] = fmaf(w[o*C_+c], xv, acc[o]);
  }
  float m=0.f;
  #pragma unroll
  for(int o=0;o<C_;o++) m += acc[o];
  m *= (1.f/C_);
  float var=0.f;
  #pragma unroll
  for(int o=0;o<C_;o++){ float d=acc[o]-m; var += d*d; }
  var *= (1.f/C_);
  float rs = rsqrtf(var+EPS_);
  float* sb = skip + (size_t)b*C_*L_ + pix;
  #pragma unroll
  for(int o=0;o<C_;o++) sb[(size_t)o*L_] = (acc[o]-m)*rs*g[o] + bb[o];
}

// ---------------------------------------------------------------------------
// K3: hp = conv1x1(skip, cv_pw)   (64 -> 128)
__global__ __launch_bounds__(256) void k3_pw(
    const float* __restrict__ skip, const float* __restrict__ w,
    float* __restrict__ hp)
{
  int t = blockIdx.x*256 + threadIdx.x;      // ((b*8+grp)*L + pix)
  int pix = t & (L_-1);
  int bg = t >> 12; int b = bg >> 3; int grp = bg & 7;
  const float* sb = skip + (size_t)b*C_*L_ + pix;
  float acc[16];
  #pragma unroll
  for(int o=0;o<16;o++) acc[o]=0.f;
  for(int c=0;c<C_;c++){
    float xv = sb[(size_t)c*L_];
    #pragma unroll
    for(int oo=0;oo<16;oo++) acc[oo]=fmaf(w[(grp*16+oo)*C_+c], xv, acc[oo]);
  }
  float* hb = hp + (size_t)b*D_*L_ + (size_t)(grp*16)*L_ + pix;
  #pragma unroll
  for(int oo=0;oo<16;oo++) hb[(size_t)oo*L_] = acc[oo];
}

// ---------------------------------------------------------------------------
// K4: hd = silu(dw3x3(hp)+cv_dwb); hdt = spatial transpose of hd.
__global__ __launch_bounds__(256) void k4_dwsilu(
    const float* __restrict__ hp, const float* __restrict__ wdw,
    const float* __restrict__ bdw, float* __restrict__ hd,
    float* __restrict__ hdt)
{
  __shared__ float tin[64][65];
  __shared__ float tout[64][65];
  int bc = blockIdx.x;                       // b*D_ + ch
  int ch = bc & (D_-1);
  const float* plane = hp + (size_t)bc*L_;
  int tid = threadIdx.x;
  #pragma unroll
  for(int qq=0;qq<16;qq++){ int lin = tid + qq*256; tin[lin>>6][lin&63] = plane[lin]; }
  __syncthreads();
  float wv[9];
  #pragma unroll
  for(int i=0;i<9;i++) wv[i] = wdw[ch*9+i];
  float bv = bdw[ch];
  float* hdp = hd + (size_t)bc*L_;
  #pragma unroll
  for(int qq=0;qq<16;qq++){
    int lin = tid + qq*256; int h = lin>>6, w = lin&63;
    float acc = bv;
    #pragma unroll
    for(int ky=0;ky<3;ky++){
      int hh = h+ky-1; if(hh<0||hh>=64) continue;
      #pragma unroll
      for(int kx=0;kx<3;kx++){
        int ww = w+kx-1; if(ww<0||ww>=64) continue;
        acc = fmaf(wv[ky*3+kx], tin[hh][ww], acc);
      }
    }
    float s = siluf_(acc);
    hdp[lin] = s;
    tout[h][w] = s;
  }
  __syncthreads();
  float* hdtp = hdt + (size_t)bc*L_;
  #pragma unroll
  for(int qq=0;qq<16;qq++){
    int lin = tid + qq*256;
    hdtp[lin] = tout[lin&63][lin>>6];        // stride-65 LDS column read: conflict-free
  }
}

// ---------------------------------------------------------------------------
// K5: xdbl = xp . xs ; store xd4 (dt-rank proj), Bs, Cs.
// xd4 layout [bk][l][4]; Bs/Cs layout [bk][l][16]  (sequence-indexed).
__global__ __launch_bounds__(256) void k5_proj(
    const float* __restrict__ hd, const float* __restrict__ hdt,
    const float* __restrict__ xp, float* __restrict__ xd4,
    float* __restrict__ bsb, float* __restrict__ csb)
{
  int l = blockIdx.x*256 + threadIdx.x;
  int k = blockIdx.y, b = blockIdx.z;
  int pixv = (k<2)? l : (L_-1-l);
  const float* src = ((k&1)? hdt : hd) + (size_t)b*D_*L_ + pixv;
  const float* xpk = xp + k*36*D_;
  float xd[36];
  #pragma unroll
  for(int c=0;c<36;c++) xd[c]=0.f;
  for(int d=0;d<D_;d++){
    float u = src[(size_t)d*L_];
    #pragma unroll
    for(int c=0;c<36;c++) xd[c] = fmaf(xpk[c*D_+d], u, xd[c]);
  }
  int bk = b*K_+k;
  float4* xq = (float4*)(xd4 + ((size_t)bk*L_ + l)*4);
  *xq = make_float4(xd[0], xd[1], xd[2], xd[3]);
  float* bp = bsb + ((size_t)bk*L_ + l)*N_;
  float* cp = csb + ((size_t)bk*L_ + l)*N_;
  #pragma unroll
  for(int n=0;n<N_;n++){ bp[n]=xd[4+n]; cp[n]=xd[20+n]; }
}

// ---------------------------------------------------------------------------
// Scan block design: block = (chunk, k, b), 128 threads = d.
// u tile (128 d x 64 l) staged in LDS (stride-65: conflict-free column reads);
// Bs/Cs/xd4 staged once per block, broadcast-read. All global IO float4-coalesced.
// ca/cb/h0 layout: [bk][c][d][n].

// K6 phase 1: per-chunk composite (a = exp(A*Sum dt), b = local end state)
__global__ __launch_bounds__(128) void k6_scan1(
    const float* __restrict__ xd4, const float* __restrict__ hd,
    const float* __restrict__ hdt, const float* __restrict__ bsb,
    const float* __restrict__ dtw, const float* __restrict__ dtb,
    const float* __restrict__ alog, float* __restrict__ ca, float* __restrict__ cb)
{
  __shared__ float su[128][65];
  __shared__ float4 sb4[64][4];
  __shared__ float4 sx[64];
  int chunk = blockIdx.x, k = blockIdx.y, b = blockIdx.z;
  int d = threadIdx.x;
  int bk = b*K_ + k;
  bool rev = (k >= 2);
  int base_l = rev ? (63-chunk)*CL_ : chunk*CL_;
  const float* src = ((k&1)? hdt : hd) + (size_t)b*D_*L_;
  #pragma unroll
  for(int p=0;p<16;p++){
    int idx = p*128 + d; int row = idx >> 4, c4 = idx & 15;
    float4 v = *(const float4*)(src + (size_t)row*L_ + base_l + c4*4);
    su[row][c4*4+0]=v.x; su[row][c4*4+1]=v.y; su[row][c4*4+2]=v.z; su[row][c4*4+3]=v.w;
  }
  const float4* bsrc = (const float4*)(bsb + ((size_t)bk*L_ + chunk*CL_)*N_);
  #pragma unroll
  for(int p=0;p<2;p++){
    int idx = p*128 + d; int row = idx>>2, q = idx&3;
    sb4[row][q] = bsrc[idx];
  }
  {
    const float4* xsrc = (const float4*)(xd4 + ((size_t)bk*L_ + chunk*CL_)*4);
    if(d < 64) sx[d] = xsrc[d];
  }
  float A[N_];
  {
    const float* al = alog + ((size_t)k*D_+d)*N_;
    #pragma unroll
    for(int n=0;n<N_;n++) A[n] = -__expf(al[n]);
  }
  float4 wv = *(const float4*)(dtw + ((size_t)k*D_+d)*R_);
  float bdt = dtb[k*D_+d];
  __syncthreads();
  float h[N_];
  #pragma unroll
  for(int n=0;n<N_;n++) h[n]=0.f;
  float S=0.f;
  for(int i=0;i<CL_;i++){
    int jj = rev ? (CL_-1-i) : i;
    float4 xv = sx[i];
    float r = fmaf(xv.x,wv.x, fmaf(xv.y,wv.y, fmaf(xv.z,wv.z, fmaf(xv.w,wv.w, bdt))));
    float dt = softplusf_(r);
    float u = su[d][jj];
    S += dt;
    float du = dt*u;
    #pragma unroll
    for(int n4=0;n4<4;n4++){
      float4 bv = sb4[i][n4];
      int n0=n4*4;
      h[n0+0] = fmaf(du, bv.x, h[n0+0]*__expf(dt*A[n0+0]));
      h[n0+1] = fmaf(du, bv.y, h[n0+1]*__expf(dt*A[n0+1]));
      h[n0+2] = fmaf(du, bv.z, h[n0+2]*__expf(dt*A[n0+2]));
      h[n0+3] = fmaf(du, bv.w, h[n0+3]*__expf(dt*A[n0+3]));
    }
  }
  size_t obase = (((size_t)bk*NC_ + chunk)*D_ + d)*N_;
  float4* cap = (float4*)(ca + obase);
  float4* cbp = (float4*)(cb + obase);
  #pragma unroll
  for(int n4=0;n4<4;n4++){
    int n0=n4*4;
    cap[n4] = make_float4(__expf(S*A[n0]), __expf(S*A[n0+1]), __expf(S*A[n0+2]), __expf(S*A[n0+3]));
    cbp[n4] = make_float4(h[n0], h[n0+1], h[n0+2], h[n0+3]);
  }
}

// K7 phase 2: sequential scan over chunk composites -> h0 per chunk
// thread = (bk, d, n); all loads/stores coalesced in [bk][c][d][n] layout
__global__ __launch_bounds__(256) void k7_scan2(
    const float* __restrict__ ca, const float* __restrict__ cb,
    float* __restrict__ h0)
{
  int t = blockIdx.x*256 + threadIdx.x;      // bk*2048 + d*16 + n
  int bk = t >> 11; int dn = t & 2047;
  size_t base = (size_t)bk*NC_*D_*N_ + dn;
  float h=0.f;
  for(int c=0;c<NC_;c++){
    size_t idx = base + (size_t)c*D_*N_;
    h0[idx] = h;
    h = fmaf(ca[idx], h, cb[idx]);
  }
}

// K8 phase 3: full scan with correct h0, emit y (+ dp*u) -> ys[bk][d][l] (seq-indexed)
__global__ __launch_bounds__(128) void k8_scan3(
    const float* __restrict__ xd4, const float* __restrict__ hd,
    const float* __restrict__ hdt, const float* __restrict__ bsb,
    const float* __restrict__ csb, const float* __restrict__ h0b,
    const float* __restrict__ dtw, const float* __restrict__ dtb,
    const float* __restrict__ alog, const float* __restrict__ dp,
    float* __restrict__ ys)
{
  __shared__ float su[128][65];
  __shared__ float4 sb4[64][4];
  __shared__ float4 sc4[64][4];
  __shared__ float4 sx[64];
  int chunk = blockIdx.x, k = blockIdx.y, b = blockIdx.z;
  int d = threadIdx.x;
  int bk = b*K_ + k;
  bool rev = (k >= 2);
  int base_l = rev ? (63-chunk)*CL_ : chunk*CL_;
  const float* src = ((k&1)? hdt : hd) + (size_t)b*D_*L_;
  #pragma unroll
  for(int p=0;p<16;p++){
    int idx = p*128 + d; int row = idx >> 4, c4 = idx & 15;
    float4 v = *(const float4*)(src + (size_t)row*L_ + base_l + c4*4);
    su[row][c4*4+0]=v.x; su[row][c4*4+1]=v.y; su[row][c4*4+2]=v.z; su[row][c4*4+3]=v.w;
  }
  const float4* bsrc = (const float4*)(bsb + ((size_t)bk*L_ + chunk*CL_)*N_);
  const float4* csrc = (const float4*)(csb + ((size_t)bk*L_ + chunk*CL_)*N_);
  #pragma unroll
  for(int p=0;p<2;p++){
    int idx = p*128 + d; int row = idx>>2, q = idx&3;
    sb4[row][q] = bsrc[idx];
    sc4[row][q] = csrc[idx];
  }
  {
    const float4* xsrc = (const float4*)(xd4 + ((size_t)bk*L_ + chunk*CL_)*4);
    if(d < 64) sx[d] = xsrc[d];
  }
  float A[N_];
  {
    const float* al = alog + ((size_t)k*D_+d)*N_;
    #pragma unroll
    for(int n=0;n<N_;n++) A[n] = -__expf(al[n]);
  }
  float4 wv = *(const float4*)(dtw + ((size_t)k*D_+d)*R_);
  float bdt = dtb[k*D_+d];
  float dpv = dp[k*D_+d];
  float h[N_];
  {
    size_t hbase = (((size_t)bk*NC_ + chunk)*D_ + d)*N_;
    const float4* h4 = (const float4*)(h0b + hbase);
    #pragma unroll
    for(int n4=0;n4<4;n4++){
      float4 hv = h4[n4];
      h[n4*4+0]=hv.x; h[n4*4+1]=hv.y; h[n4*4+2]=hv.z; h[n4*4+3]=hv.w;
    }
  }
  __syncthreads();
  for(int i=0;i<CL_;i++){
    int jj = rev ? (CL_-1-i) : i;
    float4 xv = sx[i];
    float r = fmaf(xv.x,wv.x, fmaf(xv.y,wv.y, fmaf(xv.z,wv.z, fmaf(xv.w,wv.w, bdt))));
    float dt = softplusf_(r);
    float u = su[d][jj];
    float du = dt*u;
    float y = 0.f;
    #pragma unroll
    for(int n4=0;n4<4;n4++){
      float4 bv = sb4[i][n4];
      float4 cv = sc4[i][n4];
      int n0=n4*4;
      h[n0+0] = fmaf(du, bv.x, h[n0+0]*__expf(dt*A[n0+0])); y = fmaf(h[n0+0], cv.x, y);
      h[n0+1] = fmaf(du, bv.y, h[n0+1]*__expf(dt*A[n0+1])); y = fmaf(h[n0+1], cv.y, y);
      h[n0+2] = fmaf(du, bv.z, h[n0+2]*__expf(dt*A[n0+2])); y = fmaf(h[n0+2], cv.z, y);
      h[n0+3] = fmaf(du, bv.w, h[n0+3]*__expf(dt*A[n0+3])); y = fmaf(h[n0+3], cv.w, y);
    }
    y = fmaf(dpv, u, y);
    su[d][jj] = y;                            // overwrite consumed u slot
  }
  __syncthreads();
  // coalesced copy-out: ys[(bk*D+row)*L + chunk*64 + m] = su[row][rev ? 63-m : m]
  #pragma unroll
  for(int p=0;p<16;p++){
    int idx = p*128 + d; int row = idx >> 4, c4 = idx & 15;
    int m0 = c4*4;
    float4 v;
    if(rev) v = make_float4(su[row][63-m0], su[row][62-m0], su[row][61-m0], su[row][60-m0]);
    else    v = make_float4(su[row][m0], su[row][m0+1], su[row][m0+2], su[row][m0+3]);
    *(float4*)(ys + ((size_t)bk*D_ + row)*L_ + chunk*CL_ + m0) = v;
  }
}

// ---------------------------------------------------------------------------
// K9t: combine 4 directions into yc[b][d][pix] (standard pixel order).
// block per (b,d); y1/y3 transposes via LDS stride-65 tiles; all global IO coalesced.
__global__ __launch_bounds__(256) void k9t_comb(
    const float* __restrict__ ys, float* __restrict__ yc)
{
  __shared__ float t1[64][65];
  __shared__ float t3[64][65];
  int bd = blockIdx.x; int b = bd >> 7; int d = bd & (D_-1);
  const float* y0 = ys + ((size_t)(b*K_+0)*D_ + d)*L_;
  const float* y1 = ys + ((size_t)(b*K_+1)*D_ + d)*L_;
  const float* y2 = ys + ((size_t)(b*K_+2)*D_ + d)*L_;
  const float* y3 = ys + ((size_t)(b*K_+3)*D_ + d)*L_;
  int tid = threadIdx.x;
  #pragma unroll
  for(int qq=0;qq<16;qq++){
    int lin = tid + qq*256;
    t1[lin>>6][lin&63] = y1[lin];
    t3[lin>>6][lin&63] = y3[lin];
  }
  __syncthreads();
  float* outp = yc + ((size_t)b*D_ + d)*L_;
  #pragma unroll
  for(int qq=0;qq<16;qq++){
    int lin = tid + qq*256; int h = lin>>6, w = lin&63;
    // hn[pix] = y0[pix] + y1[pixT] + y2[L-1-pix] + y3[L-1-pixT]
    // pixT = w*64+h ; L-1-pixT = (63-w)*64 + (63-h)
    outp[lin] = y0[lin] + t1[w][h] + y2[L_-1-lin] + t3[63-w][63-h];
  }
}

// K9a: LN128 over yc -> hn. block = 64 pixels x 4 d-groups; v kept in regs.
__global__ __launch_bounds__(256) void k9a_ln(
    const float* __restrict__ yc, const float* __restrict__ g,
    const float* __restrict__ bb, float* __restrict__ hn)
{
  __shared__ float ssum[4][64];
  __shared__ float ssq[4][64];
  int tid = threadIdx.x;
  int pl = tid & 63;          // pixel lane
  int wg = tid >> 6;          // d-group 0..3 (32 channels each)
  int t = blockIdx.x*64 + pl; // global b*L + pix
  int b = t >> 12; int pix = t & (L_-1);
  const float* ybase = yc + (size_t)b*D_*L_ + (size_t)(wg*32)*L_ + pix;
  float v[32];
  float s = 0.f;
  #pragma unroll
  for(int i=0;i<32;i++){ v[i] = ybase[(size_t)i*L_]; s += v[i]; }
  ssum[wg][pl] = s;
  __syncthreads();
  float S = ssum[0][pl]+ssum[1][pl]+ssum[2][pl]+ssum[3][pl];
  float m = S*(1.f/D_);
  float vq = 0.f;
  #pragma unroll
  for(int i=0;i<32;i++){ float dv = v[i]-m; vq = fmaf(dv,dv,vq); }
  ssq[wg][pl] = vq;
  __syncthreads();
  float VQ = ssq[0][pl]+ssq[1][pl]+ssq[2][pl]+ssq[3][pl];
  float rs = rsqrtf(VQ*(1.f/D_)+EPS_);
  float* hb = hn + (size_t)b*D_*L_ + (size_t)(wg*32)*L_ + pix;
  #pragma unroll
  for(int i=0;i<32;i++) hb[(size_t)i*L_] = (v[i]-m)*rs*g[wg*32+i] + bb[wg*32+i];
}

// ---------------------------------------------------------------------------
// K9b: qg = conv1x1(hn, cv_ow) + cv_skip*skip; accumulate per-(b,ch) sums
__global__ __launch_bounds__(256) void k9b_ow(
    const float* __restrict__ hn, const float* __restrict__ w,
    const float* __restrict__ skip, const float* __restrict__ cskip,
    float* __restrict__ qg, float* __restrict__ meansum)
{
  int t = blockIdx.x*256 + threadIdx.x;      // ((b*4+grp)*L + pix)
  int pix = t & (L_-1); int bg = t >> 12; int b = bg >> 2; int grp = bg & 3;
  const float* hb = hn + (size_t)b*D_*L_ + pix;
  float acc[16];
  #pragma unroll
  for(int o=0;o<16;o++) acc[o]=0.f;
  for(int dd=0;dd<D_;dd++){
    float xv = hb[(size_t)dd*L_];
    #pragma unroll
    for(int oo=0;oo<16;oo++) acc[oo]=fmaf(w[(grp*16+oo)*D_+dd], xv, acc[oo]);
  }
  float csk = cskip[0];
  const float* sb = skip + (size_t)b*C_*L_ + pix;
  float* qb = qg + (size_t)b*C_*L_ + pix;
  #pragma unroll
  for(int oo=0;oo<16;oo++){
    int o = grp*16+oo;
    float v = acc[oo] + csk*sb[(size_t)o*L_];
    qb[(size_t)o*L_] = v;
    acc[oo] = v;
  }
  #pragma unroll
  for(int oo=0;oo<16;oo++){
    float v = acc[oo];
    #pragma unroll
    for(int off=32;off>0;off>>=1) v += __shfl_down(v, off, 64);
    if((threadIdx.x & 63)==0) atomicAdd(&meansum[b*C_ + grp*16+oo], v);
  }
}

// K10: ECA — conv1d(k=3) over channel means + sigmoid -> vsig (B,64)
__global__ __launch_bounds__(256) void k10_eca(
    const float* __restrict__ meansum, const float* __restrict__ ew,
    float* __restrict__ vsig)
{
  int t = threadIdx.x; if(t >= B_*C_) return;
  int b=t>>6, c=t&63;
  const float sc = 1.f/(float)L_;
  float ml = (c>0)?  meansum[b*C_+c-1]*sc : 0.f;
  float mc =         meansum[b*C_+c]*sc;
  float mr = (c<63)? meansum[b*C_+c+1]*sc : 0.f;
  float r = ew[0]*ml + ew[1]*mc + ew[2]*mr;
  vsig[t] = sigmoidf_(r);
}

// ---------------------------------------------------------------------------
// K11: x2 = v*qg + wgm*x  (on the fly); res = LN64(conv1x1(x2,pf_nw)+pf_nb)
__global__ __launch_bounds__(64) void k11_res(
    const float* __restrict__ qg, const float* __restrict__ xin,
    const float* __restrict__ vsig, const float* __restrict__ wgm,
    const float* __restrict__ w, const float* __restrict__ nb,
    const float* __restrict__ g, const float* __restrict__ bb,
    float* __restrict__ res)
{
  int t = blockIdx.x*64 + threadIdx.x;
  int b = t >> 12, pix = t & (L_-1);
  float wg = wgm[0];
  const float* qb = qg + (size_t)b*C_*L_ + pix;
  const float* xb = xin + (size_t)b*C_*L_ + pix;
  float acc[C_];
  #pragma unroll
  for(int o=0;o<C_;o++) acc[o]=nb[o];
  for(int c=0;c<C_;c++){
    float x2 = vsig[b*C_+c]*qb[(size_t)c*L_] + wg*xb[(size_t)c*L_];
    #pragma unroll
    for(int o=0;o<C_;o++) acc[o] = fmaf(w[o*C_+c], x2, acc[o]);
  }
  float m=0.f;
  #pragma unroll
  for(int o=0;o<C_;o++) m += acc[o];
  m *= (1.f/C_);
  float var=0.f;
  #pragma unroll
  for(int o=0;o<C_;o++){ float d=acc[o]-m; var += d*d; }
  var *= (1.f/C_);
  float rs = rsqrtf(var+EPS_);
  float* rb = res + (size_t)b*C_*L_ + pix;
  #pragma unroll
  for(int o=0;o<C_;o++) rb[(size_t)o*L_] = (acc[o]-m)*rs*g[o] + bb[o];
}

// ---------------------------------------------------------------------------
// K12: cascaded depthwise convs; one block per (b, c in 0..15), plane in LDS
DEV void conv_step(const float (*tin)[65], float (*tout)[65],
                   const float* __restrict__ wp, int ks, int pad, int dil,
                   float* __restrict__ gout, int tid)
{
  for(int qq=0;qq<16;qq++){
    int lin=tid+qq*256; int h=lin>>6, w=lin&63;
    float acc=0.f;
    for(int ky=0;ky<ks;ky++){
      int hh=h+ky*dil-pad; if(hh<0||hh>=64) continue;
      for(int kx=0;kx<ks;kx++){
        int ww=w+kx*dil-pad; if(ww<0||ww>=64) continue;
        acc = fmaf(wp[ky*ks+kx], tin[hh][ww], acc);
      }
    }
    tout[h][w]=acc; gout[lin]=acc;
  }
}

__global__ __launch_bounds__(256) void k12_cascade(
    const float* __restrict__ res, const float* __restrict__ d1,
    const float* __restrict__ d2, const float* __restrict__ d3,
    const float* __restrict__ d4, float* __restrict__ cat)
{
  __shared__ float ta[64][65];
  __shared__ float tb[64][65];
  int bc = blockIdx.x; int b = bc>>4; int c = bc&15;
  int tid = threadIdx.x;
  const float* rb = res + (size_t)b*C_*L_;
  float* catb = cat + (size_t)b*C_*L_;
  for(int qq=0;qq<16;qq++){ int lin=tid+qq*256; ta[lin>>6][lin&63] = rb[(size_t)c*L_+lin]; }
  __syncthreads();
  conv_step(ta, tb, d1+c*9, 3, 1, 1, catb + (size_t)c*L_, tid);
  __syncthreads();
  for(int qq=0;qq<16;qq++){ int lin=tid+qq*256; ta[lin>>6][lin&63] = tb[lin>>6][lin&63] + rb[(size_t)(16+c)*L_+lin]; }
  __syncthreads();
  conv_step(ta, tb, d2+c*49, 7, 3, 1, catb + (size_t)(16+c)*L_, tid);
  __syncthreads();
  for(int qq=0;qq<16;qq++){ int lin=tid+qq*256; ta[lin>>6][lin&63] = tb[lin>>6][lin&63] + rb[(size_t)(32+c)*L_+lin]; }
  __syncthreads();
  conv_step(ta, tb, d3+c*9, 3, 2, 2, catb + (size_t)(32+c)*L_, tid);
  __syncthreads();
  for(int qq=0;qq<16;qq++){ int lin=tid+qq*256; ta[lin>>6][lin&63] = tb[lin>>6][lin&63] + rb[(size_t)(48+c)*L_+lin]; }
  __syncthreads();
  conv_step(ta, tb, d4+c*9, 3, 3, 3, catb + (size_t)(48+c)*L_, tid);
}

// ---------------------------------------------------------------------------
// K13: out = silu( conv1x1( LN64(cat), pf_fw ) + pf_fb ) + pf_skip*res
__global__ __launch_bounds__(64) void k13_final(
    const float* __restrict__ cat, const float* __restrict__ res,
    const float* __restrict__ g, const float* __restrict__ bb,
    const float* __restrict__ fw, const float* __restrict__ fb,
    const float* __restrict__ pskip, float* __restrict__ out)
{
  int t = blockIdx.x*64 + threadIdx.x;
  int b = t >> 12, pix = t & (L_-1);
  const float* catb = cat + (size_t)b*C_*L_ + pix;
  float s=0.f;
  for(int c=0;c<C_;c++) s += catb[(size_t)c*L_];
  float m = s*(1.f/C_);
  float var=0.f;
  for(int c=0;c<C_;c++){ float d=catb[(size_t)c*L_]-m; var += d*d; }
  var *= (1.f/C_);
  float rs = rsqrtf(var+EPS_);
  float acc[C_];
  #pragma unroll
  for(int o=0;o<C_;o++) acc[o]=fb[o];
  for(int c=0;c<C_;c++){
    float cv = (catb[(size_t)c*L_]-m)*rs*g[c]+bb[c];
    #pragma unroll
    for(int o=0;o<C_;o++) acc[o] = fmaf(fw[o*C_+c], cv, acc[o]);
  }
  float ps = pskip[0];
  const float* rb = res + (size_t)b*C_*L_ + pix;
  float* ob = out + (size_t)b*C_*L_ + pix;
  #pragma unroll
  for(int o=0;o<C_;o++) ob[(size_t)o*L_] = siluf_(acc[o]) + ps*rb[(size_t)o*L_];
}

// ---------------------------------------------------------------------------
extern "C" void kernel_launch(void* const* d_in, const int* in_sizes, int n_in,
                              void* d_out, int out_size, void* d_ws, size_t ws_size,
                              hipStream_t stream)
{
  const float* x       = (const float*)d_in[0];
  const float* wt_dw   = (const float*)d_in[1];
  const float* wt_db   = (const float*)d_in[2];
  const float* wt_lng  = (const float*)d_in[3];
  const float* wt_lnb  = (const float*)d_in[4];
  const float* wt_ctw  = (const float*)d_in[5];
  const float* wt_ctb  = (const float*)d_in[6];
  const float* cv_inw  = (const float*)d_in[7];
  const float* cv_ln1g = (const float*)d_in[8];
  const float* cv_ln1b = (const float*)d_in[9];
  const float* cv_pw   = (const float*)d_in[10];
  const float* cv_dww  = (const float*)d_in[11];
  const float* cv_dwb  = (const float*)d_in[12];
  const float* ss_xp   = (const float*)d_in[13];
  const float* ss_dtw  = (const float*)d_in[14];
  const float* ss_dtb  = (const float*)d_in[15];
  const float* ss_alog = (const float*)d_in[16];
  const float* ss_d    = (const float*)d_in[17];
  const float* cv_ong  = (const float*)d_in[18];
  const float* cv_onb  = (const float*)d_in[19];
  const float* cv_ow   = (const float*)d_in[20];
  const float* cv_skip = (const float*)d_in[21];
  const float* eca_w   = (const float*)d_in[22];
  const float* wgm_skip= (const float*)d_in[23];
  const float* pf_nw   = (const float*)d_in[24];
  const float* pf_nb   = (const float*)d_in[25];
  const float* pf_lng  = (const float*)d_in[26];
  const float* pf_lnb  = (const float*)d_in[27];
  const float* pf_d1   = (const float*)d_in[28];
  const float* pf_d2   = (const float*)d_in[29];
  const float* pf_d3   = (const float*)d_in[30];
  const float* pf_d4   = (const float*)d_in[31];
  const float* pf_flng = (const float*)d_in[32];
  const float* pf_flnb = (const float*)d_in[33];
  const float* pf_fw   = (const float*)d_in[34];
  const float* pf_fb   = (const float*)d_in[35];
  const float* pf_skip = (const float*)d_in[36];
  float* outp = (float*)d_out;

  // ---- workspace layout with aliasing ----
  float* ws = (float*)d_ws;
  size_t off = 0;
  float* q1   = ws+off; off += (size_t)B_*C4_*L_;        // 1 MB  k1->k2a
  float* q2   = ws+off;                                  // 4 MB  k2a->k2b
  float* qg   = q2;                                      //       k9b->k11 (aliases q2)
  off += (size_t)B_*C_*L_;
  float* skip = ws+off; off += (size_t)B_*C_*L_;         // 4 MB  k2b->k9b
  float* hp   = ws+off;                                  // 8 MB  k3->k4
  float* ca   = hp;                                      //       k6->k7 (aliases hp)
  off += (size_t)B_*D_*L_;
  float* hd   = ws+off;                                  // 8 MB  k4->k8
  float* res  = hd;                                      //       k11->k13 (aliases hd)
  off += (size_t)B_*D_*L_;
  float* hdt  = ws+off;                                  // 8 MB  k4->k8
  float* cat  = hdt;                                     //       k12->k13 (aliases hdt)
  off += (size_t)B_*D_*L_;
  float* xd4  = ws+off; off += (size_t)B_*K_*L_*R_;      // 1 MB  k5->k8
  float* bs   = ws+off; off += (size_t)B_*K_*L_*N_;      // 4 MB  k5->k8
  float* cs   = ws+off; off += (size_t)B_*K_*L_*N_;      // 4 MB  k5->k8
  float* cb   = ws+off;                                  // 8 MB  k6->k7
  float* hn   = cb;                                      //       k9a->k9b (aliases cb)
  off += (size_t)B_*K_*D_*NC_*N_;
  float* h0   = ws+off;                                  // 8 MB  k7->k8
  float* yc   = h0;                                      //       k9t->k9a (aliases h0, dead after k8)
  off += (size_t)B_*K_*D_*NC_*N_;
  float* ys   = ws+off; off += (size_t)B_*K_*D_*L_;      // 32 MB k8->k9t
  float* meansum = ws+off; off += 256;
  float* vsig    = ws+off; off += 256;
  (void)ws_size; (void)in_sizes; (void)n_in; (void)out_size;

  hipMemsetAsync(meansum, 0, B_*C_*sizeof(float), stream);

  k1_inln   <<<256, 64, 0, stream>>>(x, wt_dw, wt_db, wt_lng, wt_lnb, q1);
  k2a_dwtct <<<256, 256, 0, stream>>>(q1, wt_ctw, wt_ctb, q2);
  k2b_inconv_ln<<<256, 64, 0, stream>>>(q2, cv_inw, cv_ln1g, cv_ln1b, skip);
  k3_pw     <<<512, 256, 0, stream>>>(skip, cv_pw, hp);
  k4_dwsilu <<<512, 256, 0, stream>>>(hp, cv_dww, cv_dwb, hd, hdt);
  k5_proj   <<<dim3(16,4,4), 256, 0, stream>>>(hd, hdt, ss_xp, xd4, bs, cs);
  k6_scan1  <<<dim3(NC_,K_,B_), 128, 0, stream>>>(xd4, hd, hdt, bs, ss_dtw, ss_dtb, ss_alog, ca, cb);
  k7_scan2  <<<128, 256, 0, stream>>>(ca, cb, h0);
  k8_scan3  <<<dim3(NC_,K_,B_), 128, 0, stream>>>(xd4, hd, hdt, bs, cs, h0, ss_dtw, ss_dtb, ss_alog, ss_d, ys);
  k9t_comb  <<<512, 256, 0, stream>>>(ys, yc);
  k9a_ln    <<<256, 256, 0, stream>>>(yc, cv_ong, cv_onb, hn);
  k9b_ow    <<<256, 256, 0, stream>>>(hn, cv_ow, skip, cv_skip, qg, meansum);
  k10_eca   <<<1,   256, 0, stream>>>(meansum, eca_w, vsig);
  k11_res   <<<256, 64, 0, stream>>>(qg, x, vsig, wgm_skip, pf_nw, pf_nb, pf_lng, pf_lnb, res);
  k12_cascade<<<64, 256, 0, stream>>>(res, pf_d1, pf_d2, pf_d3, pf_d4, cat);
  k13_final <<<256, 64, 0, stream>>>(cat, res, pf_flng, pf_flnb, pf_fw, pf_fb, pf_skip, outp);
}

// Round 7
// 527.050 us; speedup vs baseline: 1.8479x; 1.1649x over previous
//
#include <hip/hip_runtime.h>
#include <cstdint>
#include <cstddef>

#define B_ 4
#define C_ 64
#define C4_ 16
#define D_ 128
#define H_ 64
#define W_ 64
#define L_ 4096
#define K_ 4
#define N_ 16
#define R_ 4
#define NC_ 64
#define CL_ 64
#define EPS_ 1e-6f

#define DEV __device__ __forceinline__

DEV float sigmoidf_(float x){ return 1.f/(1.f+__expf(-x)); }
DEV float siluf_(float x){ return x*sigmoidf_(x); }
// fast softplus: max(x,0) + log(1+exp(-|x|)); arg of log in [1,2] -> __logf fine
DEV float softplusf_(float x){ return fmaxf(x,0.f) + __logf(1.f+__expf(-fabsf(x))); }

// ---------------------------------------------------------------------------
// K1: q1 = LN16( conv1x1(x, wt_dw) + wt_db )   -> (B,16,H,W)
__global__ __launch_bounds__(64) void k1_inln(
    const float* __restrict__ x, const float* __restrict__ w,
    const float* __restrict__ bias, const float* __restrict__ g,
    const float* __restrict__ bb, float* __restrict__ q1)
{
  int t = blockIdx.x*64 + threadIdx.x;
  int b = t >> 12; int pix = t & (L_-1);
  const float* xb = x + (size_t)b*C_*L_ + pix;
  float acc[C4_];
  #pragma unroll
  for(int o=0;o<C4_;o++) acc[o] = bias[o];
  for(int c=0;c<C_;c++){
    float xv = xb[(size_t)c*L_];
    #pragma unroll
    for(int o=0;o<C4_;o++) acc[o] = fmaf(w[o*C_+c], xv, acc[o]);
  }
  float m=0.f;
  #pragma unroll
  for(int o=0;o<C4_;o++) m += acc[o];
  m *= (1.f/C4_);
  float var=0.f;
  #pragma unroll
  for(int o=0;o<C4_;o++){ float d=acc[o]-m; var += d*d; }
  var *= (1.f/C4_);
  float rs = rsqrtf(var+EPS_);
  float* qb = q1 + (size_t)b*C4_*L_ + pix;
  #pragma unroll
  for(int o=0;o<C4_;o++) qb[(size_t)o*L_] = (acc[o]-m)*rs*g[o] + bb[o];
}

// ---------------------------------------------------------------------------
// K2a: q2 = transposed-conv2x2( DWT_haar(q1) ) + ctb   -> (B,64,H,W)
// weights staged in LDS [pq][c(4sub*16)][o16]; 2-way broadcast reads (free).
__global__ __launch_bounds__(256) void k2a_dwtct(
    const float* __restrict__ q1, const float* __restrict__ ctw,
    const float* __restrict__ ctb, float* __restrict__ q2)
{
  __shared__ float wl[4][64][16];            // 16 KB
  int blk = blockIdx.x;                      // blk = (b*4+quarter)*16 + pixblk
  int bq = blk >> 4; int b = bq >> 2; int quarter = bq & 3;
  int tid = threadIdx.x;
  // stage 4096 weights, 16 per thread: wl[pq][c][o] = ctw[c*256 + (q*16+o)*4 + pq]
  #pragma unroll
  for(int pp=0;pp<16;pp++){
    int v = pp*256 + tid;
    int pq = v >> 10; int c = (v >> 4) & 63; int o = v & 15;
    wl[pq][c][o] = ctw[c*256 + (quarter*16+o)*4 + pq];
  }
  __syncthreads();
  int pix = ((blk & 15) << 8) + tid;
  int y = pix >> 6, xw = pix & 63;
  int i = y >> 1, p = y & 1, j = xw >> 1, q = xw & 1;
  int pq = p*2+q;
  const float* qb = q1 + (size_t)b*C4_*L_;
  int p00 = (2*i)*W_ + 2*j;
  float acc[16];
  #pragma unroll
  for(int oo=0;oo<16;oo++) acc[oo] = ctb[quarter*16+oo];
  #pragma unroll
  for(int c=0;c<16;c++){
    const float* pc = qb + (size_t)c*L_ + p00;
    float a = pc[0], bb2 = pc[1], cc = pc[W_], dd = pc[W_+1];
    float ll = (a+bb2+cc+dd)*0.5f;
    float hl = (bb2-a+dd-cc)*0.5f;
    float lh = (cc-a+dd-bb2)*0.5f;
    float hh = (a-bb2-cc+dd)*0.5f;
    const float4* wll = (const float4*)&wl[pq][c][0];
    const float4* whl = (const float4*)&wl[pq][16+c][0];
    const float4* wlh = (const float4*)&wl[pq][32+c][0];
    const float4* whh = (const float4*)&wl[pq][48+c][0];
    #pragma unroll
    for(int o4=0;o4<4;o4++){
      float4 w0 = wll[o4], w1 = whl[o4], w2 = wlh[o4], w3 = whh[o4];
      int o0 = o4*4;
      acc[o0+0] = fmaf(ll,w0.x, fmaf(hl,w1.x, fmaf(lh,w2.x, fmaf(hh,w3.x, acc[o0+0]))));
      acc[o0+1] = fmaf(ll,w0.y, fmaf(hl,w1.y, fmaf(lh,w2.y, fmaf(hh,w3.y, acc[o0+1]))));
      acc[o0+2] = fmaf(ll,w0.z, fmaf(hl,w1.z, fmaf(lh,w2.z, fmaf(hh,w3.z, acc[o0+2]))));
      acc[o0+3] = fmaf(ll,w0.w, fmaf(hl,w1.w, fmaf(lh,w2.w, fmaf(hh,w3.w, acc[o0+3]))));
    }
  }
  float* q2b = q2 + (size_t)b*C_*L_ + (size_t)(quarter*16)*L_ + pix;
  #pragma unroll
  for(int oo=0;oo<16;oo++) q2b[(size_t)oo*L_] = acc[oo];
}

// ---------------------------------------------------------------------------
// K2b: skip = LN64( conv1x1(q2, cv_inw) )   -> (B,64,H,W)
// block = 64 pixels x 4 o-groups; 16 acc/thread; LDS cross-group LN reduce.
__global__ __launch_bounds__(256) void k2b_inconv_ln(
    const float* __restrict__ q2, const float* __restrict__ w,
    const float* __restrict__ g, const float* __restrict__ bb,
    float* __restrict__ skip)
{
  __shared__ float ssum[4][64];
  __shared__ float ssq[4][64];
  int tid = threadIdx.x;
  int pl = tid & 63, wg = tid >> 6;
  int t = blockIdx.x*64 + pl;
  int b = t >> 12; int pix = t & (L_-1);
  const float* qb = q2 + (size_t)b*C_*L_ + pix;
  const float* wrow = w + wg*16*C_;
  float acc[16];
  #pragma unroll
  for(int o=0;o<16;o++) acc[o]=0.f;
  for(int c=0;c<C_;c++){
    float xv = qb[(size_t)c*L_];
    #pragma unroll
    for(int o=0;o<16;o++) acc[o] = fmaf(wrow[o*C_+c], xv, acc[o]);
  }
  float s=0.f;
  #pragma unroll
  for(int o=0;o<16;o++) s += acc[o];
  ssum[wg][pl] = s;
  __syncthreads();
  float m = (ssum[0][pl]+ssum[1][pl]+ssum[2][pl]+ssum[3][pl])*(1.f/C_);
  float vq=0.f;
  #pragma unroll
  for(int o=0;o<16;o++){ float d=acc[o]-m; vq = fmaf(d,d,vq); }
  ssq[wg][pl] = vq;
  __syncthreads();
  float var = (ssq[0][pl]+ssq[1][pl]+ssq[2][pl]+ssq[3][pl])*(1.f/C_);
  float rs = rsqrtf(var+EPS_);
  float* sb = skip + (size_t)b*C_*L_ + (size_t)(wg*16)*L_ + pix;
  #pragma unroll
  for(int o=0;o<16;o++) sb[(size_t)o*L_] = (acc[o]-m)*rs*g[wg*16+o] + bb[wg*16+o];
}

// ---------------------------------------------------------------------------
// K3: hp = conv1x1(skip, cv_pw)   (64 -> 128)
__global__ __launch_bounds__(256) void k3_pw(
    const float* __restrict__ skip, const float* __restrict__ w,
    float* __restrict__ hp)
{
  int t = blockIdx.x*256 + threadIdx.x;      // ((b*8+grp)*L + pix)
  int pix = t & (L_-1);
  int bg = t >> 12; int b = bg >> 3; int grp = bg & 7;
  const float* sb = skip + (size_t)b*C_*L_ + pix;
  float acc[16];
  #pragma unroll
  for(int o=0;o<16;o++) acc[o]=0.f;
  for(int c=0;c<C_;c++){
    float xv = sb[(size_t)c*L_];
    #pragma unroll
    for(int oo=0;oo<16;oo++) acc[oo]=fmaf(w[(grp*16+oo)*C_+c], xv, acc[oo]);
  }
  float* hb = hp + (size_t)b*D_*L_ + (size_t)(grp*16)*L_ + pix;
  #pragma unroll
  for(int oo=0;oo<16;oo++) hb[(size_t)oo*L_] = acc[oo];
}

// ---------------------------------------------------------------------------
// K4: hd = silu(dw3x3(hp)+cv_dwb); hdt = spatial transpose of hd.
__global__ __launch_bounds__(256) void k4_dwsilu(
    const float* __restrict__ hp, const float* __restrict__ wdw,
    const float* __restrict__ bdw, float* __restrict__ hd,
    float* __restrict__ hdt)
{
  __shared__ float tin[64][65];
  __shared__ float tout[64][65];
  int bc = blockIdx.x;                       // b*D_ + ch
  int ch = bc & (D_-1);
  const float* plane = hp + (size_t)bc*L_;
  int tid = threadIdx.x;
  #pragma unroll
  for(int qq=0;qq<16;qq++){ int lin = tid + qq*256; tin[lin>>6][lin&63] = plane[lin]; }
  __syncthreads();
  float wv[9];
  #pragma unroll
  for(int i=0;i<9;i++) wv[i] = wdw[ch*9+i];
  float bv = bdw[ch];
  float* hdp = hd + (size_t)bc*L_;
  #pragma unroll
  for(int qq=0;qq<16;qq++){
    int lin = tid + qq*256; int h = lin>>6, w = lin&63;
    float acc = bv;
    #pragma unroll
    for(int ky=0;ky<3;ky++){
      int hh = h+ky-1; if(hh<0||hh>=64) continue;
      #pragma unroll
      for(int kx=0;kx<3;kx++){
        int ww = w+kx-1; if(ww<0||ww>=64) continue;
        acc = fmaf(wv[ky*3+kx], tin[hh][ww], acc);
      }
    }
    float s = siluf_(acc);
    hdp[lin] = s;
    tout[h][w] = s;
  }
  __syncthreads();
  float* hdtp = hdt + (size_t)bc*L_;
  #pragma unroll
  for(int qq=0;qq<16;qq++){
    int lin = tid + qq*256;
    hdtp[lin] = tout[lin&63][lin>>6];        // stride-65 LDS column read: conflict-free
  }
}

// ---------------------------------------------------------------------------
// K5: xdbl = xp . xs ; store xd4 (dt-rank proj), Bs, Cs.
// xd4 layout [bk][l][4]; Bs/Cs layout [bk][l][16]  (sequence-indexed).
__global__ __launch_bounds__(256) void k5_proj(
    const float* __restrict__ hd, const float* __restrict__ hdt,
    const float* __restrict__ xp, float* __restrict__ xd4,
    float* __restrict__ bsb, float* __restrict__ csb)
{
  int l = blockIdx.x*256 + threadIdx.x;
  int k = blockIdx.y, b = blockIdx.z;
  int pixv = (k<2)? l : (L_-1-l);
  const float* src = ((k&1)? hdt : hd) + (size_t)b*D_*L_ + pixv;
  const float* xpk = xp + k*36*D_;
  float xd[36];
  #pragma unroll
  for(int c=0;c<36;c++) xd[c]=0.f;
  for(int d=0;d<D_;d++){
    float u = src[(size_t)d*L_];
    #pragma unroll
    for(int c=0;c<36;c++) xd[c] = fmaf(xpk[c*D_+d], u, xd[c]);
  }
  int bk = b*K_+k;
  float4* xq = (float4*)(xd4 + ((size_t)bk*L_ + l)*4);
  *xq = make_float4(xd[0], xd[1], xd[2], xd[3]);
  float* bp = bsb + ((size_t)bk*L_ + l)*N_;
  float* cp = csb + ((size_t)bk*L_ + l)*N_;
  #pragma unroll
  for(int n=0;n<N_;n++){ bp[n]=xd[4+n]; cp[n]=xd[20+n]; }
}

// ---------------------------------------------------------------------------
// Scan block design: block = (chunk, k, b), 128 threads = d.

// K6 phase 1: per-chunk composite (a = exp(A*Sum dt), b = local end state)
__global__ __launch_bounds__(128) void k6_scan1(
    const float* __restrict__ xd4, const float* __restrict__ hd,
    const float* __restrict__ hdt, const float* __restrict__ bsb,
    const float* __restrict__ dtw, const float* __restrict__ dtb,
    const float* __restrict__ alog, float* __restrict__ ca, float* __restrict__ cb)
{
  __shared__ float su[128][65];
  __shared__ float4 sb4[64][4];
  __shared__ float4 sx[64];
  int chunk = blockIdx.x, k = blockIdx.y, b = blockIdx.z;
  int d = threadIdx.x;
  int bk = b*K_ + k;
  bool rev = (k >= 2);
  int base_l = rev ? (63-chunk)*CL_ : chunk*CL_;
  const float* src = ((k&1)? hdt : hd) + (size_t)b*D_*L_;
  #pragma unroll
  for(int p=0;p<16;p++){
    int idx = p*128 + d; int row = idx >> 4, c4 = idx & 15;
    float4 v = *(const float4*)(src + (size_t)row*L_ + base_l + c4*4);
    su[row][c4*4+0]=v.x; su[row][c4*4+1]=v.y; su[row][c4*4+2]=v.z; su[row][c4*4+3]=v.w;
  }
  const float4* bsrc = (const float4*)(bsb + ((size_t)bk*L_ + chunk*CL_)*N_);
  #pragma unroll
  for(int p=0;p<2;p++){
    int idx = p*128 + d; int row = idx>>2, q = idx&3;
    sb4[row][q] = bsrc[idx];
  }
  {
    const float4* xsrc = (const float4*)(xd4 + ((size_t)bk*L_ + chunk*CL_)*4);
    if(d < 64) sx[d] = xsrc[d];
  }
  float A[N_];
  {
    const float* al = alog + ((size_t)k*D_+d)*N_;
    #pragma unroll
    for(int n=0;n<N_;n++) A[n] = -__expf(al[n]);
  }
  float4 wv = *(const float4*)(dtw + ((size_t)k*D_+d)*R_);
  float bdt = dtb[k*D_+d];
  __syncthreads();
  float h[N_];
  #pragma unroll
  for(int n=0;n<N_;n++) h[n]=0.f;
  float S=0.f;
  for(int i=0;i<CL_;i++){
    int jj = rev ? (CL_-1-i) : i;
    float4 xv = sx[i];
    float r = fmaf(xv.x,wv.x, fmaf(xv.y,wv.y, fmaf(xv.z,wv.z, fmaf(xv.w,wv.w, bdt))));
    float dt = softplusf_(r);
    float u = su[d][jj];
    S += dt;
    float du = dt*u;
    #pragma unroll
    for(int n4=0;n4<4;n4++){
      float4 bv = sb4[i][n4];
      int n0=n4*4;
      h[n0+0] = fmaf(du, bv.x, h[n0+0]*__expf(dt*A[n0+0]));
      h[n0+1] = fmaf(du, bv.y, h[n0+1]*__expf(dt*A[n0+1]));
      h[n0+2] = fmaf(du, bv.z, h[n0+2]*__expf(dt*A[n0+2]));
      h[n0+3] = fmaf(du, bv.w, h[n0+3]*__expf(dt*A[n0+3]));
    }
  }
  size_t obase = (((size_t)bk*NC_ + chunk)*D_ + d)*N_;
  float4* cap = (float4*)(ca + obase);
  float4* cbp = (float4*)(cb + obase);
  #pragma unroll
  for(int n4=0;n4<4;n4++){
    int n0=n4*4;
    cap[n4] = make_float4(__expf(S*A[n0]), __expf(S*A[n0+1]), __expf(S*A[n0+2]), __expf(S*A[n0+3]));
    cbp[n4] = make_float4(h[n0], h[n0+1], h[n0+2], h[n0+3]);
  }
}

// K7 phase 2: sequential scan over chunk composites -> h0 per chunk
__global__ __launch_bounds__(256) void k7_scan2(
    const float* __restrict__ ca, const float* __restrict__ cb,
    float* __restrict__ h0)
{
  int t = blockIdx.x*256 + threadIdx.x;      // bk*2048 + d*16 + n
  int bk = t >> 11; int dn = t & 2047;
  size_t base = (size_t)bk*NC_*D_*N_ + dn;
  float h=0.f;
  for(int c=0;c<NC_;c++){
    size_t idx = base + (size_t)c*D_*N_;
    h0[idx] = h;
    h = fmaf(ca[idx], h, cb[idx]);
  }
}

// K8 phase 3: full scan with correct h0, emit y (+ dp*u) -> ys[bk][d][l] (seq-indexed)
__global__ __launch_bounds__(128) void k8_scan3(
    const float* __restrict__ xd4, const float* __restrict__ hd,
    const float* __restrict__ hdt, const float* __restrict__ bsb,
    const float* __restrict__ csb, const float* __restrict__ h0b,
    const float* __restrict__ dtw, const float* __restrict__ dtb,
    const float* __restrict__ alog, const float* __restrict__ dp,
    float* __restrict__ ys)
{
  __shared__ float su[128][65];
  __shared__ float4 sb4[64][4];
  __shared__ float4 sc4[64][4];
  __shared__ float4 sx[64];
  int chunk = blockIdx.x, k = blockIdx.y, b = blockIdx.z;
  int d = threadIdx.x;
  int bk = b*K_ + k;
  bool rev = (k >= 2);
  int base_l = rev ? (63-chunk)*CL_ : chunk*CL_;
  const float* src = ((k&1)? hdt : hd) + (size_t)b*D_*L_;
  #pragma unroll
  for(int p=0;p<16;p++){
    int idx = p*128 + d; int row = idx >> 4, c4 = idx & 15;
    float4 v = *(const float4*)(src + (size_t)row*L_ + base_l + c4*4);
    su[row][c4*4+0]=v.x; su[row][c4*4+1]=v.y; su[row][c4*4+2]=v.z; su[row][c4*4+3]=v.w;
  }
  const float4* bsrc = (const float4*)(bsb + ((size_t)bk*L_ + chunk*CL_)*N_);
  const float4* csrc = (const float4*)(csb + ((size_t)bk*L_ + chunk*CL_)*N_);
  #pragma unroll
  for(int p=0;p<2;p++){
    int idx = p*128 + d; int row = idx>>2, q = idx&3;
    sb4[row][q] = bsrc[idx];
    sc4[row][q] = csrc[idx];
  }
  {
    const float4* xsrc = (const float4*)(xd4 + ((size_t)bk*L_ + chunk*CL_)*4);
    if(d < 64) sx[d] = xsrc[d];
  }
  float A[N_];
  {
    const float* al = alog + ((size_t)k*D_+d)*N_;
    #pragma unroll
    for(int n=0;n<N_;n++) A[n] = -__expf(al[n]);
  }
  float4 wv = *(const float4*)(dtw + ((size_t)k*D_+d)*R_);
  float bdt = dtb[k*D_+d];
  float dpv = dp[k*D_+d];
  float h[N_];
  {
    size_t hbase = (((size_t)bk*NC_ + chunk)*D_ + d)*N_;
    const float4* h4 = (const float4*)(h0b + hbase);
    #pragma unroll
    for(int n4=0;n4<4;n4++){
      float4 hv = h4[n4];
      h[n4*4+0]=hv.x; h[n4*4+1]=hv.y; h[n4*4+2]=hv.z; h[n4*4+3]=hv.w;
    }
  }
  __syncthreads();
  for(int i=0;i<CL_;i++){
    int jj = rev ? (CL_-1-i) : i;
    float4 xv = sx[i];
    float r = fmaf(xv.x,wv.x, fmaf(xv.y,wv.y, fmaf(xv.z,wv.z, fmaf(xv.w,wv.w, bdt))));
    float dt = softplusf_(r);
    float u = su[d][jj];
    float du = dt*u;
    float y = 0.f;
    #pragma unroll
    for(int n4=0;n4<4;n4++){
      float4 bv = sb4[i][n4];
      float4 cv = sc4[i][n4];
      int n0=n4*4;
      h[n0+0] = fmaf(du, bv.x, h[n0+0]*__expf(dt*A[n0+0])); y = fmaf(h[n0+0], cv.x, y);
      h[n0+1] = fmaf(du, bv.y, h[n0+1]*__expf(dt*A[n0+1])); y = fmaf(h[n0+1], cv.y, y);
      h[n0+2] = fmaf(du, bv.z, h[n0+2]*__expf(dt*A[n0+2])); y = fmaf(h[n0+2], cv.z, y);
      h[n0+3] = fmaf(du, bv.w, h[n0+3]*__expf(dt*A[n0+3])); y = fmaf(h[n0+3], cv.w, y);
    }
    y = fmaf(dpv, u, y);
    su[d][jj] = y;                            // overwrite consumed u slot
  }
  __syncthreads();
  // coalesced copy-out: ys[(bk*D+row)*L + chunk*64 + m] = su[row][rev ? 63-m : m]
  #pragma unroll
  for(int p=0;p<16;p++){
    int idx = p*128 + d; int row = idx >> 4, c4 = idx & 15;
    int m0 = c4*4;
    float4 v;
    if(rev) v = make_float4(su[row][63-m0], su[row][62-m0], su[row][61-m0], su[row][60-m0]);
    else    v = make_float4(su[row][m0], su[row][m0+1], su[row][m0+2], su[row][m0+3]);
    *(float4*)(ys + ((size_t)bk*D_ + row)*L_ + chunk*CL_ + m0) = v;
  }
}

// ---------------------------------------------------------------------------
// K9t: combine 4 directions into yc[b][d][pix] (standard pixel order).
__global__ __launch_bounds__(256) void k9t_comb(
    const float* __restrict__ ys, float* __restrict__ yc)
{
  __shared__ float t1[64][65];
  __shared__ float t3[64][65];
  int bd = blockIdx.x; int b = bd >> 7; int d = bd & (D_-1);
  const float* y0 = ys + ((size_t)(b*K_+0)*D_ + d)*L_;
  const float* y1 = ys + ((size_t)(b*K_+1)*D_ + d)*L_;
  const float* y2 = ys + ((size_t)(b*K_+2)*D_ + d)*L_;
  const float* y3 = ys + ((size_t)(b*K_+3)*D_ + d)*L_;
  int tid = threadIdx.x;
  #pragma unroll
  for(int qq=0;qq<16;qq++){
    int lin = tid + qq*256;
    t1[lin>>6][lin&63] = y1[lin];
    t3[lin>>6][lin&63] = y3[lin];
  }
  __syncthreads();
  float* outp = yc + ((size_t)b*D_ + d)*L_;
  #pragma unroll
  for(int qq=0;qq<16;qq++){
    int lin = tid + qq*256; int h = lin>>6, w = lin&63;
    outp[lin] = y0[lin] + t1[w][h] + y2[L_-1-lin] + t3[63-w][63-h];
  }
}

// K9a: LN128 over yc -> hn. block = 64 pixels x 4 d-groups; v kept in regs.
__global__ __launch_bounds__(256) void k9a_ln(
    const float* __restrict__ yc, const float* __restrict__ g,
    const float* __restrict__ bb, float* __restrict__ hn)
{
  __shared__ float ssum[4][64];
  __shared__ float ssq[4][64];
  int tid = threadIdx.x;
  int pl = tid & 63;          // pixel lane
  int wg = tid >> 6;          // d-group 0..3 (32 channels each)
  int t = blockIdx.x*64 + pl; // global b*L + pix
  int b = t >> 12; int pix = t & (L_-1);
  const float* ybase = yc + (size_t)b*D_*L_ + (size_t)(wg*32)*L_ + pix;
  float v[32];
  float s = 0.f;
  #pragma unroll
  for(int i=0;i<32;i++){ v[i] = ybase[(size_t)i*L_]; s += v[i]; }
  ssum[wg][pl] = s;
  __syncthreads();
  float S = ssum[0][pl]+ssum[1][pl]+ssum[2][pl]+ssum[3][pl];
  float m = S*(1.f/D_);
  float vq = 0.f;
  #pragma unroll
  for(int i=0;i<32;i++){ float dv = v[i]-m; vq = fmaf(dv,dv,vq); }
  ssq[wg][pl] = vq;
  __syncthreads();
  float VQ = ssq[0][pl]+ssq[1][pl]+ssq[2][pl]+ssq[3][pl];
  float rs = rsqrtf(VQ*(1.f/D_)+EPS_);
  float* hb = hn + (size_t)b*D_*L_ + (size_t)(wg*32)*L_ + pix;
  #pragma unroll
  for(int i=0;i<32;i++) hb[(size_t)i*L_] = (v[i]-m)*rs*g[wg*32+i] + bb[wg*32+i];
}

// ---------------------------------------------------------------------------
// K9b: qg = conv1x1(hn, cv_ow) + cv_skip*skip; accumulate per-(b,ch) sums
__global__ __launch_bounds__(256) void k9b_ow(
    const float* __restrict__ hn, const float* __restrict__ w,
    const float* __restrict__ skip, const float* __restrict__ cskip,
    float* __restrict__ qg, float* __restrict__ meansum)
{
  int t = blockIdx.x*256 + threadIdx.x;      // ((b*4+grp)*L + pix)
  int pix = t & (L_-1); int bg = t >> 12; int b = bg >> 2; int grp = bg & 3;
  const float* hb = hn + (size_t)b*D_*L_ + pix;
  float acc[16];
  #pragma unroll
  for(int o=0;o<16;o++) acc[o]=0.f;
  for(int dd=0;dd<D_;dd++){
    float xv = hb[(size_t)dd*L_];
    #pragma unroll
    for(int oo=0;oo<16;oo++) acc[oo]=fmaf(w[(grp*16+oo)*D_+dd], xv, acc[oo]);
  }
  float csk = cskip[0];
  const float* sb = skip + (size_t)b*C_*L_ + pix;
  float* qb = qg + (size_t)b*C_*L_ + pix;
  #pragma unroll
  for(int oo=0;oo<16;oo++){
    int o = grp*16+oo;
    float v = acc[oo] + csk*sb[(size_t)o*L_];
    qb[(size_t)o*L_] = v;
    acc[oo] = v;
  }
  #pragma unroll
  for(int oo=0;oo<16;oo++){
    float v = acc[oo];
    #pragma unroll
    for(int off=32;off>0;off>>=1) v += __shfl_down(v, off, 64);
    if((threadIdx.x & 63)==0) atomicAdd(&meansum[b*C_ + grp*16+oo], v);
  }
}

// K10: ECA — conv1d(k=3) over channel means + sigmoid -> vsig (B,64)
__global__ __launch_bounds__(256) void k10_eca(
    const float* __restrict__ meansum, const float* __restrict__ ew,
    float* __restrict__ vsig)
{
  int t = threadIdx.x; if(t >= B_*C_) return;
  int b=t>>6, c=t&63;
  const float sc = 1.f/(float)L_;
  float ml = (c>0)?  meansum[b*C_+c-1]*sc : 0.f;
  float mc =         meansum[b*C_+c]*sc;
  float mr = (c<63)? meansum[b*C_+c+1]*sc : 0.f;
  float r = ew[0]*ml + ew[1]*mc + ew[2]*mr;
  vsig[t] = sigmoidf_(r);
}

// ---------------------------------------------------------------------------
// K11: x2 = v*qg + wgm*x; res = LN64(conv1x1(x2,pf_nw)+pf_nb)
// block = 64 pixels x 4 o-groups; LDS cross-group LN reduce.
__global__ __launch_bounds__(256) void k11_res(
    const float* __restrict__ qg, const float* __restrict__ xin,
    const float* __restrict__ vsig, const float* __restrict__ wgm,
    const float* __restrict__ w, const float* __restrict__ nb,
    const float* __restrict__ g, const float* __restrict__ bb,
    float* __restrict__ res)
{
  __shared__ float ssum[4][64];
  __shared__ float ssq[4][64];
  int tid = threadIdx.x;
  int pl = tid & 63, wg2 = tid >> 6;
  int t = blockIdx.x*64 + pl;
  int b = t >> 12; int pix = t & (L_-1);
  float wgs = wgm[0];
  const float* qb = qg + (size_t)b*C_*L_ + pix;
  const float* xb = xin + (size_t)b*C_*L_ + pix;
  const float* wrow = w + wg2*16*C_;
  float acc[16];
  #pragma unroll
  for(int o=0;o<16;o++) acc[o]=nb[wg2*16+o];
  for(int c=0;c<C_;c++){
    float x2 = vsig[b*C_+c]*qb[(size_t)c*L_] + wgs*xb[(size_t)c*L_];
    #pragma unroll
    for(int o=0;o<16;o++) acc[o] = fmaf(wrow[o*C_+c], x2, acc[o]);
  }
  float s=0.f;
  #pragma unroll
  for(int o=0;o<16;o++) s += acc[o];
  ssum[wg2][pl] = s;
  __syncthreads();
  float m = (ssum[0][pl]+ssum[1][pl]+ssum[2][pl]+ssum[3][pl])*(1.f/C_);
  float vq=0.f;
  #pragma unroll
  for(int o=0;o<16;o++){ float d=acc[o]-m; vq = fmaf(d,d,vq); }
  ssq[wg2][pl] = vq;
  __syncthreads();
  float var = (ssq[0][pl]+ssq[1][pl]+ssq[2][pl]+ssq[3][pl])*(1.f/C_);
  float rs = rsqrtf(var+EPS_);
  float* rb = res + (size_t)b*C_*L_ + (size_t)(wg2*16)*L_ + pix;
  #pragma unroll
  for(int o=0;o<16;o++) rb[(size_t)o*L_] = (acc[o]-m)*rs*g[wg2*16+o] + bb[wg2*16+o];
}

// ---------------------------------------------------------------------------
// K12: cascaded depthwise convs; one block per (b, c in 0..15), plane in LDS
DEV void conv_step(const float (*tin)[65], float (*tout)[65],
                   const float* __restrict__ wp, int ks, int pad, int dil,
                   float* __restrict__ gout, int tid)
{
  for(int qq=0;qq<16;qq++){
    int lin=tid+qq*256; int h=lin>>6, w=lin&63;
    float acc=0.f;
    for(int ky=0;ky<ks;ky++){
      int hh=h+ky*dil-pad; if(hh<0||hh>=64) continue;
      for(int kx=0;kx<ks;kx++){
        int ww=w+kx*dil-pad; if(ww<0||ww>=64) continue;
        acc = fmaf(wp[ky*ks+kx], tin[hh][ww], acc);
      }
    }
    tout[h][w]=acc; gout[lin]=acc;
  }
}

__global__ __launch_bounds__(256) void k12_cascade(
    const float* __restrict__ res, const float* __restrict__ d1,
    const float* __restrict__ d2, const float* __restrict__ d3,
    const float* __restrict__ d4, float* __restrict__ cat)
{
  __shared__ float ta[64][65];
  __shared__ float tb[64][65];
  int bc = blockIdx.x; int b = bc>>4; int c = bc&15;
  int tid = threadIdx.x;
  const float* rb = res + (size_t)b*C_*L_;
  float* catb = cat + (size_t)b*C_*L_;
  for(int qq=0;qq<16;qq++){ int lin=tid+qq*256; ta[lin>>6][lin&63] = rb[(size_t)c*L_+lin]; }
  __syncthreads();
  conv_step(ta, tb, d1+c*9, 3, 1, 1, catb + (size_t)c*L_, tid);
  __syncthreads();
  for(int qq=0;qq<16;qq++){ int lin=tid+qq*256; ta[lin>>6][lin&63] = tb[lin>>6][lin&63] + rb[(size_t)(16+c)*L_+lin]; }
  __syncthreads();
  conv_step(ta, tb, d2+c*49, 7, 3, 1, catb + (size_t)(16+c)*L_, tid);
  __syncthreads();
  for(int qq=0;qq<16;qq++){ int lin=tid+qq*256; ta[lin>>6][lin&63] = tb[lin>>6][lin&63] + rb[(size_t)(32+c)*L_+lin]; }
  __syncthreads();
  conv_step(ta, tb, d3+c*9, 3, 2, 2, catb + (size_t)(32+c)*L_, tid);
  __syncthreads();
  for(int qq=0;qq<16;qq++){ int lin=tid+qq*256; ta[lin>>6][lin&63] = tb[lin>>6][lin&63] + rb[(size_t)(48+c)*L_+lin]; }
  __syncthreads();
  conv_step(ta, tb, d4+c*9, 3, 3, 3, catb + (size_t)(48+c)*L_, tid);
}

// ---------------------------------------------------------------------------
// K13: out = silu( conv1x1( LN64(cat), pf_fw ) + pf_fb ) + pf_skip*res
// thread = (b, grp of 16 o, pix); inputs in regs, stats computed locally.
__global__ __launch_bounds__(256) void k13_final(
    const float* __restrict__ cat, const float* __restrict__ res,
    const float* __restrict__ g, const float* __restrict__ bb,
    const float* __restrict__ fw, const float* __restrict__ fb,
    const float* __restrict__ pskip, float* __restrict__ out)
{
  int t = blockIdx.x*256 + threadIdx.x;      // ((b*4+grp)*L + pix)
  int pix = t & (L_-1); int bg = t >> 12; int b = bg >> 2; int grp = bg & 3;
  const float* catb = cat + (size_t)b*C_*L_ + pix;
  float cv[C_];
  float s=0.f;
  #pragma unroll
  for(int c=0;c<C_;c++){ cv[c] = catb[(size_t)c*L_]; s += cv[c]; }
  float m = s*(1.f/C_);
  float var=0.f;
  #pragma unroll
  for(int c=0;c<C_;c++){ float d=cv[c]-m; var = fmaf(d,d,var); }
  var *= (1.f/C_);
  float rs = rsqrtf(var+EPS_);
  const float* wrow = fw + grp*16*C_;
  float acc[16];
  #pragma unroll
  for(int o=0;o<16;o++) acc[o]=fb[grp*16+o];
  #pragma unroll
  for(int c=0;c<C_;c++){
    float nv = (cv[c]-m)*rs*g[c]+bb[c];
    #pragma unroll
    for(int o=0;o<16;o++) acc[o] = fmaf(wrow[o*C_+c], nv, acc[o]);
  }
  float ps = pskip[0];
  const float* rb = res + (size_t)b*C_*L_ + (size_t)(grp*16)*L_ + pix;
  float* ob = out + (size_t)b*C_*L_ + (size_t)(grp*16)*L_ + pix;
  #pragma unroll
  for(int o=0;o<16;o++) ob[(size_t)o*L_] = siluf_(acc[o]) + ps*rb[(size_t)o*L_];
}

// ---------------------------------------------------------------------------
extern "C" void kernel_launch(void* const* d_in, const int* in_sizes, int n_in,
                              void* d_out, int out_size, void* d_ws, size_t ws_size,
                              hipStream_t stream)
{
  const float* x       = (const float*)d_in[0];
  const float* wt_dw   = (const float*)d_in[1];
  const float* wt_db   = (const float*)d_in[2];
  const float* wt_lng  = (const float*)d_in[3];
  const float* wt_lnb  = (const float*)d_in[4];
  const float* wt_ctw  = (const float*)d_in[5];
  const float* wt_ctb  = (const float*)d_in[6];
  const float* cv_inw  = (const float*)d_in[7];
  const float* cv_ln1g = (const float*)d_in[8];
  const float* cv_ln1b = (const float*)d_in[9];
  const float* cv_pw   = (const float*)d_in[10];
  const float* cv_dww  = (const float*)d_in[11];
  const float* cv_dwb  = (const float*)d_in[12];
  const float* ss_xp   = (const float*)d_in[13];
  const float* ss_dtw  = (const float*)d_in[14];
  const float* ss_dtb  = (const float*)d_in[15];
  const float* ss_alog = (const float*)d_in[16];
  const float* ss_d    = (const float*)d_in[17];
  const float* cv_ong  = (const float*)d_in[18];
  const float* cv_onb  = (const float*)d_in[19];
  const float* cv_ow   = (const float*)d_in[20];
  const float* cv_skip = (const float*)d_in[21];
  const float* eca_w   = (const float*)d_in[22];
  const float* wgm_skip= (const float*)d_in[23];
  const float* pf_nw   = (const float*)d_in[24];
  const float* pf_nb   = (const float*)d_in[25];
  const float* pf_lng  = (const float*)d_in[26];
  const float* pf_lnb  = (const float*)d_in[27];
  const float* pf_d1   = (const float*)d_in[28];
  const float* pf_d2   = (const float*)d_in[29];
  const float* pf_d3   = (const float*)d_in[30];
  const float* pf_d4   = (const float*)d_in[31];
  const float* pf_flng = (const float*)d_in[32];
  const float* pf_flnb = (const float*)d_in[33];
  const float* pf_fw   = (const float*)d_in[34];
  const float* pf_fb   = (const float*)d_in[35];
  const float* pf_skip = (const float*)d_in[36];
  float* outp = (float*)d_out;

  // ---- workspace layout with aliasing ----
  float* ws = (float*)d_ws;
  size_t off = 0;
  float* q1   = ws+off; off += (size_t)B_*C4_*L_;        // 1 MB  k1->k2a
  float* q2   = ws+off;                                  // 4 MB  k2a->k2b
  float* qg   = q2;                                      //       k9b->k11 (aliases q2)
  off += (size_t)B_*C_*L_;
  float* skip = ws+off; off += (size_t)B_*C_*L_;         // 4 MB  k2b->k9b
  float* hp   = ws+off;                                  // 8 MB  k3->k4
  float* ca   = hp;                                      //       k6->k7 (aliases hp)
  off += (size_t)B_*D_*L_;
  float* hd   = ws+off;                                  // 8 MB  k4->k8
  float* res  = hd;                                      //       k11->k13 (aliases hd)
  off += (size_t)B_*D_*L_;
  float* hdt  = ws+off;                                  // 8 MB  k4->k8
  float* cat  = hdt;                                     //       k12->k13 (aliases hdt)
  off += (size_t)B_*D_*L_;
  float* xd4  = ws+off; off += (size_t)B_*K_*L_*R_;      // 1 MB  k5->k8
  float* bs   = ws+off; off += (size_t)B_*K_*L_*N_;      // 4 MB  k5->k8
  float* cs   = ws+off; off += (size_t)B_*K_*L_*N_;      // 4 MB  k5->k8
  float* cb   = ws+off;                                  // 8 MB  k6->k7
  float* hn   = cb;                                      //       k9a->k9b (aliases cb)
  off += (size_t)B_*K_*D_*NC_*N_;
  float* h0   = ws+off;                                  // 8 MB  k7->k8
  float* yc   = h0;                                      //       k9t->k9a (aliases h0, dead after k8)
  off += (size_t)B_*K_*D_*NC_*N_;
  float* ys   = ws+off; off += (size_t)B_*K_*D_*L_;      // 32 MB k8->k9t
  float* meansum = ws+off; off += 256;
  float* vsig    = ws+off; off += 256;
  (void)ws_size; (void)in_sizes; (void)n_in; (void)out_size;

  hipMemsetAsync(meansum, 0, B_*C_*sizeof(float), stream);

  k1_inln   <<<256, 64, 0, stream>>>(x, wt_dw, wt_db, wt_lng, wt_lnb, q1);
  k2a_dwtct <<<256, 256, 0, stream>>>(q1, wt_ctw, wt_ctb, q2);
  k2b_inconv_ln<<<256, 256, 0, stream>>>(q2, cv_inw, cv_ln1g, cv_ln1b, skip);
  k3_pw     <<<512, 256, 0, stream>>>(skip, cv_pw, hp);
  k4_dwsilu <<<512, 256, 0, stream>>>(hp, cv_dww, cv_dwb, hd, hdt);
  k5_proj   <<<dim3(16,4,4), 256, 0, stream>>>(hd, hdt, ss_xp, xd4, bs, cs);
  k6_scan1  <<<dim3(NC_,K_,B_), 128, 0, stream>>>(xd4, hd, hdt, bs, ss_dtw, ss_dtb, ss_alog, ca, cb);
  k7_scan2  <<<128, 256, 0, stream>>>(ca, cb, h0);
  k8_scan3  <<<dim3(NC_,K_,B_), 128, 0, stream>>>(xd4, hd, hdt, bs, cs, h0, ss_dtw, ss_dtb, ss_alog, ss_d, ys);
  k9t_comb  <<<512, 256, 0, stream>>>(ys, yc);
  k9a_ln    <<<256, 256, 0, stream>>>(yc, cv_ong, cv_onb, hn);
  k9b_ow    <<<256, 256, 0, stream>>>(hn, cv_ow, skip, cv_skip, qg, meansum);
  k10_eca   <<<1,   256, 0, stream>>>(meansum, eca_w, vsig);
  k11_res   <<<256, 256, 0, stream>>>(qg, x, vsig, wgm_skip, pf_nw, pf_nb, pf_lng, pf_lnb, res);
  k12_cascade<<<64, 256, 0, stream>>>(res, pf_d1, pf_d2, pf_d3, pf_d4, cat);
  k13_final <<<256, 256, 0, stream>>>(cat, res, pf_flng, pf_flnb, pf_fw, pf_fb, pf_skip, outp);
}